// Round 12
// baseline (377.249 us; speedup 1.0000x reference)
//
#include <hip/hip_runtime.h>
#include <hip/hip_bf16.h>

#define NB 2
#define NN 2048
#define ND 256
#define NS 16
#define NDC 4
#define NDI 512
#define NDTR 16
#define LCH 32    // chunk length for parallel scan
#define NCH 64    // number of chunks (LCH*NCH == NN)

typedef __hip_bfloat16 bf16;
typedef __attribute__((ext_vector_type(8))) __bf16 bf16x8;
typedef __attribute__((ext_vector_type(4))) float f32x4;

__device__ __forceinline__ float b2f(bf16 h) { return __bfloat162float(h); }

__device__ __forceinline__ void dec8(const uint4 u, float w[8]) {
    union { unsigned u; float f; } c;
    c.u = u.x << 16;          w[0] = c.f;
    c.u = u.x & 0xffff0000u;  w[1] = c.f;
    c.u = u.y << 16;          w[2] = c.f;
    c.u = u.y & 0xffff0000u;  w[3] = c.f;
    c.u = u.z << 16;          w[4] = c.f;
    c.u = u.z & 0xffff0000u;  w[5] = c.f;
    c.u = u.w << 16;          w[6] = c.f;
    c.u = u.w & 0xffff0000u;  w[7] = c.f;
}

// ---------------- K0: convert/copy WEIGHT inputs to bf16 + flag + zero pooled/counter ----------------
struct CvtArgs { const void* s[21]; };
__device__ __constant__ const int seg_cum[22] = {
    0, 1048576, 2097152, 3145728, 3146496, 3147264, 3933696, 3939840,
    3941376, 4015104, 4039680, 4041216, 4065792, 4067328, 4460544, 4460545,
    4657153, 4657409, 4658177, 4658180, 4854788, 4855044 };
__device__ __constant__ const int seg_dst[21] = {
    0,        1048576,  2097152,  4847616, 4848384, 3145728, 4841472, 4849152, 4325376,
    4399104,  4850688,  4423680,  4852224, 3932160, 4855056, 4448256, 4853760, 4854016,
    4854784,  4644864,  4854800 };

__global__ __launch_bounds__(256) void k_convert(CvtArgs a, int* __restrict__ flag,
                                                 bf16* __restrict__ dst,
                                                 float* __restrict__ pooled)
{
    int idx0 = blockIdx.x * 256 + threadIdx.x;
    unsigned v0 = ((const unsigned*)a.s[3])[0];
    int f = ((v0 & 0xFFFFu) == 0u) ? 1 : 0;
    if (idx0 == 0) { flag[0] = f; flag[1] = 0; }   // flag[1] = outproj ticket counter
    if (idx0 < 1536) pooled[idx0] = 0.0f;
    int idx = idx0 + 3145728;              // features handled by k_ln
    if (idx >= 4855044) return;
    int seg = 3;
    #pragma unroll
    for (int i = 4; i < 21; i++) if (idx >= seg_cum[i]) seg = i;
    int off = idx - seg_cum[seg];
    bf16 v;
    if (f) v = __float2bfloat16(((const float*)a.s[seg])[off]);
    else   v = ((const bf16*)a.s[seg])[off];
    dst[seg_dst[seg] + off] = v;
}

// ---------------- K1: layernorm + feature conversion (reads raw inputs) ----------------
__global__ __launch_bounds__(256) void k_ln(
    const void* __restrict__ e, const void* __restrict__ bl, const void* __restrict__ sp,
    const void* __restrict__ nw_raw, const void* __restrict__ nb_raw,
    bf16* __restrict__ cvt_in, bf16* __restrict__ xn)
{
    int row = blockIdx.x;            // sb*NN + n, sb = s*NB + b
    int sb = row >> 11, n = row & (NN - 1);
    int s = sb >> 1, b = sb & 1;
    int t = threadIdx.x;
    unsigned v0 = ((const unsigned*)nw_raw)[0];
    int f = ((v0 & 0xFFFFu) == 0u);
    const void* xin = (s == 0) ? e : ((s == 1) ? bl : sp);
    size_t gi = ((size_t)(b << 11) + n) * ND + t;
    float v = f ? ((const float*)xin)[gi] : b2f(((const bf16*)xin)[gi]);
    cvt_in[(size_t)s * 1048576 + gi] = __float2bfloat16(v);
    float s1 = v, s2 = v * v;
    #pragma unroll
    for (int m = 1; m < 64; m <<= 1) { s1 += __shfl_xor(s1, m); s2 += __shfl_xor(s2, m); }
    __shared__ float r1[4], r2[4];
    int w = t >> 6;
    if ((t & 63) == 0) { r1[w] = s1; r2[w] = s2; }
    __syncthreads();
    float mean = (r1[0] + r1[1] + r1[2] + r1[3]) * (1.0f / ND);
    float ms   = (r2[0] + r2[1] + r2[2] + r2[3]) * (1.0f / ND);
    float inv = rsqrtf(ms - mean * mean + 1e-5f);
    float wv = f ? ((const float*)nw_raw)[s * ND + t] : b2f(((const bf16*)nw_raw)[s * ND + t]);
    float bv = f ? ((const float*)nb_raw)[s * ND + t] : b2f(((const bf16*)nb_raw)[s * ND + t]);
    xn[(size_t)row * ND + t] = __float2bfloat16((v - mean) * inv * wv + bv);
}

// ---------------- K2: in_proj MFMA 128x128 + FUSED causal conv + silu ----------------
// bn<4 -> xc columns: conv+silu applied in epilogue, writes xa. bn>=4 -> z written directly.
// Halo rows (n-1..n-3) computed via extra MFMAs from xnx staging (zero-padded at tile start).
__global__ __launch_bounds__(256) void k_inproj_t(
    const bf16* __restrict__ xn, const bf16* __restrict__ in_w,
    const bf16* __restrict__ conv_w, const bf16* __restrict__ conv_b,
    bf16* __restrict__ xa, bf16* __restrict__ z)
{
    __shared__ bf16 sh[2 * 128 * 72];     // As | Bs, reused as conv tile T[131][136]
    __shared__ bf16 xnx[4][72];
    bf16* As = sh;
    bf16* Bs = sh + 128 * 72;
    int bid = blockIdx.x;
    int bm = bid >> 3, bn = bid & 7;           // 96 x 8
    int m0 = bm * 128, e0 = bn * 128;
    int s = m0 >> 12;
    int nn0 = m0 & (NN - 1);
    bool doConv  = (bn < 4);
    bool doExtra = doConv && (nn0 != 0);
    const bf16* W = in_w + (size_t)s * (2 * NDI) * ND;
    int t = threadIdx.x;
    int w = t >> 6, l = t & 63;
    int wm = w >> 1, wn = w & 1;
    int quad = l >> 4, lan = l & 15;
    f32x4 acc[4][4];
    #pragma unroll
    for (int mi = 0; mi < 4; mi++)
        #pragma unroll
        for (int j = 0; j < 4; j++) acc[mi][j] = (f32x4){0.f, 0.f, 0.f, 0.f};
    f32x4 accx[4];
    #pragma unroll
    for (int j = 0; j < 4; j++) accx[j] = (f32x4){0.f, 0.f, 0.f, 0.f};
    for (int kc0 = 0; kc0 < 256; kc0 += 64) {
        __syncthreads();
        #pragma unroll
        for (int i = 0; i < 4; i++) {
            int li = i * 256 + t;
            int row = li >> 3, col = (li & 7) * 8;
            *(uint4*)&As[row * 72 + col] =
                *(const uint4*)(xn + (size_t)(m0 + row) * ND + kc0 + col);
        }
        #pragma unroll
        for (int i = 0; i < 4; i++) {
            int li = i * 256 + t;
            int row = li >> 3, col = (li & 7) * 8;
            *(uint4*)&Bs[row * 72 + col] =
                *(const uint4*)(W + (size_t)(e0 + row) * ND + kc0 + col);
        }
        if (doExtra && t < 24) {
            int i = t >> 3, q = t & 7;
            *(uint4*)&xnx[i][q * 8] =
                *(const uint4*)(xn + (size_t)(m0 - 3 + i) * ND + kc0 + q * 8);
        }
        __syncthreads();
        #pragma unroll
        for (int kc = 0; kc < 64; kc += 32) {
            bf16x8 af[4], bf[4];
            #pragma unroll
            for (int mi = 0; mi < 4; mi++)
                af[mi] = *(const bf16x8*)&As[(wm * 64 + mi * 16 + lan) * 72 + kc + quad * 8];
            #pragma unroll
            for (int j = 0; j < 4; j++)
                bf[j] = *(const bf16x8*)&Bs[(wn * 64 + j * 16 + lan) * 72 + kc + quad * 8];
            #pragma unroll
            for (int mi = 0; mi < 4; mi++)
                #pragma unroll
                for (int j = 0; j < 4; j++)
                    acc[mi][j] = __builtin_amdgcn_mfma_f32_16x16x32_bf16(af[mi], bf[j], acc[mi][j], 0, 0, 0);
            if (doExtra && wm == 0) {
                bf16x8 ax = *(const bf16x8*)&xnx[lan & 3][kc + quad * 8];
                #pragma unroll
                for (int j = 0; j < 4; j++)
                    accx[j] = __builtin_amdgcn_mfma_f32_16x16x32_bf16(ax, bf[j], accx[j], 0, 0, 0);
            }
        }
    }
    __syncthreads();   // all LDS reads done; sh reusable
    if (!doConv) {
        // z epilogue (e0 >= 512)
        int ebase = e0 & (NDI - 1);
        #pragma unroll
        for (int mi = 0; mi < 4; mi++) {
            #pragma unroll
            for (int j = 0; j < 4; j++) {
                int ec = ebase + wn * 64 + j * 16 + lan;
                #pragma unroll
                for (int r = 0; r < 4; r++) {
                    int m = m0 + wm * 64 + mi * 16 + quad * 4 + r;
                    z[(size_t)m * NDI + ec] = __float2bfloat16(acc[mi][j][r]);
                }
            }
        }
        return;
    }
    // ---- conv path: spill pre-activation tile T[131][136] into sh ----
    bf16* T = sh;
    #pragma unroll
    for (int mi = 0; mi < 4; mi++) {
        #pragma unroll
        for (int j = 0; j < 4; j++) {
            int el = wn * 64 + j * 16 + lan;
            #pragma unroll
            for (int r = 0; r < 4; r++) {
                int lm = wm * 64 + mi * 16 + quad * 4 + r;
                T[(3 + lm) * 136 + el] = __float2bfloat16(acc[mi][j][r]);
            }
        }
    }
    if (wm == 0 && quad == 0) {
        #pragma unroll
        for (int j = 0; j < 4; j++) {
            int el = wn * 64 + j * 16 + lan;
            #pragma unroll
            for (int r = 0; r < 3; r++)
                T[r * 136 + el] = doExtra ? __float2bfloat16(accx[j][r]) : __float2bfloat16(0.0f);
        }
    }
    __syncthreads();
    // ---- conv + silu + store xa ----
    int cg = t & 15;                   // column group fixed per thread
    int col8 = cg * 8;
    int d8 = e0 + col8;
    const uint4* cwp = (const uint4*)(conv_w + ((size_t)s * NDI + d8) * NDC);
    float cwf[32];
    dec8(cwp[0], cwf); dec8(cwp[1], cwf + 8); dec8(cwp[2], cwf + 16); dec8(cwp[3], cwf + 24);
    float bias[8];
    dec8(*(const uint4*)(conv_b + (size_t)s * NDI + d8), bias);
    #pragma unroll
    for (int i = 0; i < 8; i++) {
        int ro = i * 16 + (t >> 4);    // 0..127
        float x0[8], x1[8], x2[8], x3[8];
        dec8(*(const uint4*)&T[(ro + 0) * 136 + col8], x0);   // x[n-3]
        dec8(*(const uint4*)&T[(ro + 1) * 136 + col8], x1);   // x[n-2]
        dec8(*(const uint4*)&T[(ro + 2) * 136 + col8], x2);   // x[n-1]
        dec8(*(const uint4*)&T[(ro + 3) * 136 + col8], x3);   // x[n]
        union { bf16 h[8]; uint4 u; } o;
        #pragma unroll
        for (int jj = 0; jj < 8; jj++) {
            float a = bias[jj] + cwf[jj * 4 + 0] * x0[jj] + cwf[jj * 4 + 1] * x1[jj]
                    + cwf[jj * 4 + 2] * x2[jj] + cwf[jj * 4 + 3] * x3[jj];
            a = a / (1.0f + __expf(-a));
            o.h[jj] = __float2bfloat16(a);
        }
        *(uint4*)(xa + (size_t)(m0 + ro) * NDI + d8) = o.u;
    }
}

// ---------------- K4a: x_proj MFMA, split-K x4 -> xpart[4][12288][48] fp32 ----------------
__global__ __launch_bounds__(256) void k_xproj_t(
    const bf16* __restrict__ xa, const bf16* __restrict__ xproj_w,
    float* __restrict__ xpart)
{
    __shared__ bf16 As[64 * 72];
    __shared__ bf16 Bs[48 * 72];
    int bid = blockIdx.x;
    int bm = bid >> 2, ks = bid & 3;       // 192 x 4
    int m0 = bm * 64;
    int s = m0 >> 12;
    const bf16* W = xproj_w + (size_t)s * 48 * NDI;
    int t = threadIdx.x;
    int w = t >> 6, l = t & 63;
    int quad = l >> 4, lan = l & 15;
    f32x4 acc[3];
    #pragma unroll
    for (int j = 0; j < 3; j++) acc[j] = (f32x4){0.f, 0.f, 0.f, 0.f};
    for (int kc0 = ks * 128; kc0 < ks * 128 + 128; kc0 += 64) {
        __syncthreads();
        #pragma unroll
        for (int i = 0; i < 2; i++) {          // A: 64x64 = 512 uint4
            int li = i * 256 + t;
            int row = li >> 3, col = (li & 7) * 8;
            *(uint4*)&As[row * 72 + col] =
                *(const uint4*)(xa + (size_t)(m0 + row) * NDI + kc0 + col);
        }
        {
            int li = t;                        // B: 48x64 = 384 uint4
            if (li < 384) {
                int row = li >> 3, col = (li & 7) * 8;
                *(uint4*)&Bs[row * 72 + col] =
                    *(const uint4*)(W + (size_t)row * NDI + kc0 + col);
            }
            int li2 = 256 + t;
            if (li2 < 384) {
                int row = li2 >> 3, col = (li2 & 7) * 8;
                *(uint4*)&Bs[row * 72 + col] =
                    *(const uint4*)(W + (size_t)row * NDI + kc0 + col);
            }
        }
        __syncthreads();
        #pragma unroll
        for (int kc = 0; kc < 64; kc += 32) {
            bf16x8 af = *(const bf16x8*)&As[(w * 16 + lan) * 72 + kc + quad * 8];
            #pragma unroll
            for (int j = 0; j < 3; j++) {
                bf16x8 bf = *(const bf16x8*)&Bs[(j * 16 + lan) * 72 + kc + quad * 8];
                acc[j] = __builtin_amdgcn_mfma_f32_16x16x32_bf16(af, bf, acc[j], 0, 0, 0);
            }
        }
    }
    float* dst = xpart + (size_t)ks * (12288 * 48);
    #pragma unroll
    for (int j = 0; j < 3; j++) {
        int e = j * 16 + lan;
        #pragma unroll
        for (int r = 0; r < 4; r++) {
            int m = m0 + w * 16 + quad * 4 + r;
            dst[(size_t)m * 48 + e] = acc[j][r];
        }
    }
}

// ---------------- K4b: reduce split-K + dt GEMM (K=16) + softplus ----------------
__global__ __launch_bounds__(256) void k_dt2(
    const float* __restrict__ xpart, const bf16* __restrict__ dt_w,
    const bf16* __restrict__ dt_b, float* __restrict__ xdbl, bf16* __restrict__ dt)
{
    __shared__ float xs[4][48];
    int row0 = blockIdx.x * 4;
    int s = row0 >> 12;
    int t = threadIdx.x;
    if (t < 192) {
        int r = t / 48, e = t % 48;
        size_t base = (size_t)(row0 + r) * 48 + e;
        const size_t seg = (size_t)12288 * 48;
        float v = xpart[base] + xpart[base + seg] + xpart[base + 2 * seg] + xpart[base + 3 * seg];
        xs[r][e] = v;
        if (e >= 16) xdbl[base] = v;    // B and C columns for the scans
    }
    __syncthreads();
    #pragma unroll
    for (int dd = 0; dd < 2; dd++) {
        int d = t + dd * 256;
        const uint4* wp = (const uint4*)(dt_w + ((size_t)s * NDI + d) * NDTR);
        float w[16]; dec8(wp[0], w); dec8(wp[1], w + 8);
        float bias = b2f(dt_b[s * NDI + d]);
        #pragma unroll
        for (int r = 0; r < 4; r++) {
            float a = bias;
            #pragma unroll
            for (int j = 0; j < 16; j++) a += w[j] * xs[r][j];
            a = (a > 20.0f) ? a : log1pf(__expf(a));   // softplus
            dt[(size_t)(row0 + r) * NDI + d] = __float2bfloat16(a);
        }
    }
}

// ---------------- K5a: chunk-local scan (LDS-staged) -> Hend, Pprod ----------------
__global__ __launch_bounds__(256) void k_scan1(
    const bf16* __restrict__ dt, const bf16* __restrict__ xa,
    const bf16* __restrict__ A_log, const float* __restrict__ xdbl,
    float* __restrict__ Hend, float* __restrict__ Pprod)
{
    __shared__ bf16 dts[LCH * 256];
    __shared__ bf16 xas[LCH * 256];
    __shared__ float Bs[LCH * NS];
    int bid = blockIdx.x;                 // 6 * NCH * 2 = 768
    int sb = bid / (NCH * 2);
    int rem = bid % (NCH * 2);
    int chunk = rem >> 1, dg = rem & 1;
    int s = sb >> 1;
    int t = threadIdx.x;
    int d = dg * 256 + t;
    int n0 = chunk * LCH;
    size_t rowbase = (size_t)sb * NN;
    const bf16* dtg = dt + (rowbase + n0) * NDI + dg * 256;
    const bf16* xag = xa + (rowbase + n0) * NDI + dg * 256;
    #pragma unroll
    for (int i = 0; i < 4; i++) {
        int li = i * 256 + t;
        int row = li >> 5, q = li & 31;
        ((uint4*)dts)[li] = *(const uint4*)(dtg + (size_t)row * NDI + q * 8);
        ((uint4*)xas)[li] = *(const uint4*)(xag + (size_t)row * NDI + q * 8);
    }
    if (t < 128) {
        int row = t >> 2, q = t & 3;
        ((float4*)Bs)[t] = ((const float4*)(xdbl + (rowbase + n0 + row) * 48 + 16))[q];
    }
    float A[16];
    {
        const uint4* ap = (const uint4*)(A_log + ((size_t)s * NDI + d) * NS);
        float al[8]; dec8(ap[0], al);
        #pragma unroll
        for (int i = 0; i < 8; i++) A[i] = -__expf(al[i]);
        dec8(ap[1], al);
        #pragma unroll
        for (int i = 0; i < 8; i++) A[8 + i] = -__expf(al[i]);
    }
    __syncthreads();
    float h[16], P[16];
    #pragma unroll
    for (int i = 0; i < 16; i++) { h[i] = 0.0f; P[i] = 1.0f; }
    #pragma unroll 4
    for (int nl = 0; nl < LCH; nl++) {
        float dtv = b2f(dts[nl * 256 + t]);
        float xav = b2f(xas[nl * 256 + t]);
        float bcom = dtv * xav;
        const float4* br = (const float4*)&Bs[nl * NS];
        float4 b0 = br[0], b1 = br[1], b2 = br[2], b3 = br[3];
        float bv[16] = {b0.x,b0.y,b0.z,b0.w,b1.x,b1.y,b1.z,b1.w,
                        b2.x,b2.y,b2.z,b2.w,b3.x,b3.y,b3.z,b3.w};
        #pragma unroll
        for (int st = 0; st < 16; st++) {
            float dA = __expf(dtv * A[st]);
            h[st] = dA * h[st] + bcom * bv[st];
            P[st] *= dA;
        }
    }
    size_t base = ((size_t)(chunk * 6 + sb) * NS) * NDI + d;
    #pragma unroll
    for (int st = 0; st < 16; st++) {
        Hend[base + (size_t)st * NDI] = h[st];
        Pprod[base + (size_t)st * NDI] = P[st];
    }
}

// ---------------- K5b: prefix over chunk summaries, parallel over states ----------------
__global__ __launch_bounds__(256) void k_scomb(float* __restrict__ Hend, const float* __restrict__ Pprod)
{
    int idx = blockIdx.x * 256 + threadIdx.x;   // 49152 = 6 sb * 16 st * 512 d
    int sb = idx >> 13;
    int rem = idx & 8191;
    int st = rem >> 9, d = rem & 511;
    float h = 0.0f;
    const size_t stride = (size_t)6 * NS * NDI;
    size_t g = ((size_t)sb * NS + st) * NDI + d;
    #pragma unroll 4
    for (int c = 0; c < NCH; c++) {
        float He = Hend[g], Pp = Pprod[g];
        Hend[g] = h;                 // h_start for this chunk
        h = He + Pp * h;
        g += stride;
    }
}

// ---------------- K5c: re-scan chunks from h_start (LDS-staged), C-dot + gating -> y ----------------
__global__ __launch_bounds__(256) void k_scan2(
    const bf16* __restrict__ dt, const bf16* __restrict__ xa, const bf16* __restrict__ z,
    const float* __restrict__ xdbl,
    const bf16* __restrict__ A_log, const bf16* __restrict__ Dp,
    const float* __restrict__ Hstart, bf16* __restrict__ y)
{
    __shared__ bf16 dts[LCH * 256];
    __shared__ bf16 xas[LCH * 256];
    __shared__ bf16 zs[LCH * 256];
    __shared__ float Bs[LCH * NS], Cs[LCH * NS];
    int bid = blockIdx.x;
    int sb = bid / (NCH * 2);
    int rem = bid % (NCH * 2);
    int chunk = rem >> 1, dg = rem & 1;
    int s = sb >> 1;
    int t = threadIdx.x;
    int d = dg * 256 + t;
    int n0 = chunk * LCH;
    size_t rowbase = (size_t)sb * NN;
    const bf16* dtg = dt + (rowbase + n0) * NDI + dg * 256;
    const bf16* xag = xa + (rowbase + n0) * NDI + dg * 256;
    const bf16* zg  = z  + (rowbase + n0) * NDI + dg * 256;
    #pragma unroll
    for (int i = 0; i < 4; i++) {
        int li = i * 256 + t;
        int row = li >> 5, q = li & 31;
        ((uint4*)dts)[li] = *(const uint4*)(dtg + (size_t)row * NDI + q * 8);
        ((uint4*)xas)[li] = *(const uint4*)(xag + (size_t)row * NDI + q * 8);
        ((uint4*)zs)[li]  = *(const uint4*)(zg  + (size_t)row * NDI + q * 8);
    }
    if (t < 128) {
        int row = t >> 2, q = t & 3;
        ((float4*)Bs)[t] = ((const float4*)(xdbl + (rowbase + n0 + row) * 48 + 16))[q];
    } else {
        int t2 = t - 128;
        int row = t2 >> 2, q = t2 & 3;
        ((float4*)Cs)[t2] = ((const float4*)(xdbl + (rowbase + n0 + row) * 48 + 32))[q];
    }
    float A[16];
    {
        const uint4* ap = (const uint4*)(A_log + ((size_t)s * NDI + d) * NS);
        float al[8]; dec8(ap[0], al);
        #pragma unroll
        for (int i = 0; i < 8; i++) A[i] = -__expf(al[i]);
        dec8(ap[1], al);
        #pragma unroll
        for (int i = 0; i < 8; i++) A[8 + i] = -__expf(al[i]);
    }
    float Dpv = b2f(Dp[s * NDI + d]);
    float h[16];
    {
        size_t base = ((size_t)(chunk * 6 + sb) * NS) * NDI + d;
        #pragma unroll
        for (int st = 0; st < 16; st++) h[st] = Hstart[base + (size_t)st * NDI];
    }
    __syncthreads();
    bf16* yp = y + (rowbase + n0) * NDI + d;
    #pragma unroll 4
    for (int nl = 0; nl < LCH; nl++) {
        float dtv = b2f(dts[nl * 256 + t]);
        float xav = b2f(xas[nl * 256 + t]);
        float zz  = b2f(zs[nl * 256 + t]);
        float bcom = dtv * xav;
        const float4* br = (const float4*)&Bs[nl * NS];
        const float4* cr = (const float4*)&Cs[nl * NS];
        float4 b0 = br[0], b1 = br[1], b2 = br[2], b3 = br[3];
        float4 c0 = cr[0], c1 = cr[1], c2 = cr[2], c3 = cr[3];
        float bv[16] = {b0.x,b0.y,b0.z,b0.w,b1.x,b1.y,b1.z,b1.w,
                        b2.x,b2.y,b2.z,b2.w,b3.x,b3.y,b3.z,b3.w};
        float cv[16] = {c0.x,c0.y,c0.z,c0.w,c1.x,c1.y,c1.z,c1.w,
                        c2.x,c2.y,c2.z,c2.w,c3.x,c3.y,c3.z,c3.w};
        float yacc = 0.0f;
        #pragma unroll
        for (int st = 0; st < 16; st++) {
            float dA = __expf(dtv * A[st]);
            h[st] = dA * h[st] + bcom * bv[st];
            yacc += h[st] * cv[st];
        }
        float yv = yacc + xav * Dpv;
        yv *= zz / (1.0f + __expf(-zz));
        yp[(size_t)nl * NDI] = __float2bfloat16(yv);
    }
}

// ---------------- K6: out_proj MFMA + residual + pooling; last block computes coeffs ----------------
__global__ __launch_bounds__(256) void k_outproj_t(
    const bf16* __restrict__ y, const bf16* __restrict__ out_w,
    const bf16* __restrict__ e_, const bf16* __restrict__ bl, const bf16* __restrict__ sp,
    bf16* __restrict__ proc, float* __restrict__ pooled,
    const bf16* __restrict__ agg_w1, const bf16* __restrict__ agg_b1,
    const bf16* __restrict__ agg_w2, const bf16* __restrict__ agg_b2,
    const bf16* __restrict__ temp, float* __restrict__ coeffs,
    int* __restrict__ fc)
{
    __shared__ bf16 As[128 * 72];
    __shared__ bf16 Bs[64 * 72];
    __shared__ float colsum[64];
    __shared__ int lastf;
    int bid = blockIdx.x;
    int bm = bid >> 2, bn = bid & 3;
    int m0 = bm * 128, e0 = bn * 64;
    int s = m0 >> 12;
    const bf16* W = out_w + (size_t)s * ND * NDI;
    int t = threadIdx.x;
    int w = t >> 6, l = t & 63;
    int quad = l >> 4, lan = l & 15;
    f32x4 acc[2][4];
    #pragma unroll
    for (int mi = 0; mi < 2; mi++)
        #pragma unroll
        for (int j = 0; j < 4; j++) acc[mi][j] = (f32x4){0.f, 0.f, 0.f, 0.f};
    for (int kc0 = 0; kc0 < 512; kc0 += 64) {
        __syncthreads();
        #pragma unroll
        for (int i = 0; i < 4; i++) {
            int li = i * 256 + t;
            int row = li >> 3, col = (li & 7) * 8;
            *(uint4*)&As[row * 72 + col] =
                *(const uint4*)(y + (size_t)(m0 + row) * NDI + kc0 + col);
        }
        #pragma unroll
        for (int i = 0; i < 2; i++) {
            int li = i * 256 + t;
            int row = li >> 3, col = (li & 7) * 8;
            *(uint4*)&Bs[row * 72 + col] =
                *(const uint4*)(W + (size_t)(e0 + row) * NDI + kc0 + col);
        }
        __syncthreads();
        #pragma unroll
        for (int kc = 0; kc < 64; kc += 32) {
            bf16x8 af[2], bf[4];
            #pragma unroll
            for (int mi = 0; mi < 2; mi++)
                af[mi] = *(const bf16x8*)&As[(w * 32 + mi * 16 + lan) * 72 + kc + quad * 8];
            #pragma unroll
            for (int j = 0; j < 4; j++)
                bf[j] = *(const bf16x8*)&Bs[(j * 16 + lan) * 72 + kc + quad * 8];
            #pragma unroll
            for (int mi = 0; mi < 2; mi++)
                #pragma unroll
                for (int j = 0; j < 4; j++)
                    acc[mi][j] = __builtin_amdgcn_mfma_f32_16x16x32_bf16(af[mi], bf[j], acc[mi][j], 0, 0, 0);
        }
    }
    if (t < 64) colsum[t] = 0.0f;
    __syncthreads();
    const bf16* xin = (s == 0) ? e_ : ((s == 1) ? bl : sp);
    int b = (m0 >> 11) & 1;
    #pragma unroll
    for (int mi = 0; mi < 2; mi++) {
        #pragma unroll
        for (int j = 0; j < 4; j++) {
            int e = e0 + j * 16 + lan;
            float ps = 0.0f;
            #pragma unroll
            for (int r = 0; r < 4; r++) {
                int m = m0 + w * 32 + mi * 16 + quad * 4 + r;
                int n = m & (NN - 1);
                float v = acc[mi][j][r] + b2f(xin[((size_t)(b * NN + n)) * ND + e]);
                proc[(size_t)m * ND + e] = __float2bfloat16(v);
                ps += v;
            }
            atomicAdd(&colsum[j * 16 + lan], ps);
        }
    }
    __syncthreads();
    if (t < 64) atomicAdd(&pooled[b * 768 + s * 256 + e0 + t], colsum[t]);
    // ---- ticket: last block computes coeffs ----
    __threadfence();
    if (t == 0) lastf = (atomicAdd(&fc[1], 1) == (int)gridDim.x - 1);
    __syncthreads();
    if (!lastf) return;
    float* plds = (float*)Bs;          // 1536 + 256 + 3 floats fit in Bs (9216 B)
    float* hbb  = plds + 1536;
    float* lgg  = hbb + 256;
    for (int i = t; i < 1536; i += 256)
        plds[i] = __hip_atomic_load(&pooled[i], __ATOMIC_RELAXED, __HIP_MEMORY_SCOPE_AGENT);
    __syncthreads();
    for (int bb = 0; bb < NB; bb++) {
        float dot = 0.0f;
        const uint4* wp = (const uint4*)(agg_w1 + (size_t)t * 768);
        for (int k8 = 0; k8 < 96; k8++) {
            float wv[8]; dec8(wp[k8], wv);
            const float* pp = plds + bb * 768 + k8 * 8;
            #pragma unroll
            for (int j = 0; j < 8; j++) dot += wv[j] * pp[j];
        }
        float x = b2f(agg_b1[t]) + dot * (1.0f / NN);
        float inner = 0.7978845608028654f * (x + 0.044715f * x * x * x);
        hbb[t] = 0.5f * x * (1.0f + tanhf(inner));
        __syncthreads();
        if (t < 3) {
            float ll = b2f(agg_b2[t]);
            const bf16* w2 = agg_w2 + t * 256;
            for (int d2 = 0; d2 < 256; d2++) ll += b2f(w2[d2]) * hbb[d2];
            lgg[t] = ll;
        }
        __syncthreads();
        if (t == 0) {
            float m = fmaxf(lgg[0], fmaxf(lgg[1], lgg[2]));
            float e0f = __expf(lgg[0] - m), e1 = __expf(lgg[1] - m), e2 = __expf(lgg[2] - m);
            float iS = 1.0f / (e0f + e1 + e2);
            float c0 = e0f * iS, c1 = e1 * iS, c2 = e2 * iS;
            float tt = b2f(temp[0]) + 1e-6f;
            float m2 = fmaxf(c0, fmaxf(c1, c2)) / tt;
            e0f = __expf(c0 / tt - m2); e1 = __expf(c1 / tt - m2); e2 = __expf(c2 / tt - m2);
            iS = 1.0f / (e0f + e1 + e2);
            coeffs[bb * 3 + 0] = e0f * iS;
            coeffs[bb * 3 + 1] = e1 * iS;
            coeffs[bb * 3 + 2] = e2 * iS;
        }
        __syncthreads();
    }
}

// ---------------- K9: final proj tiled MFMA + weighted residual -> d_out ----------------
__global__ __launch_bounds__(256) void k_final_t(
    const bf16* __restrict__ proc, const bf16* __restrict__ proj_w,
    const bf16* __restrict__ proj_b, const float* __restrict__ coeffs,
    const int* __restrict__ flag, void* __restrict__ out)
{
    __shared__ bf16 As[128 * 72];
    __shared__ bf16 Bs[64 * 72];
    int bid = blockIdx.x;
    int bm = bid >> 2, bn = bid & 3;
    int m0 = bm * 128, e0 = bn * 64;
    int b = m0 >> 11;                 // batch, const per block
    int nbase = m0 & (NN - 1);
    int t = threadIdx.x;
    int w = t >> 6, l = t & 63;
    int quad = l >> 4, lan = l & 15;
    f32x4 acc[2][4];
    #pragma unroll
    for (int mi = 0; mi < 2; mi++)
        #pragma unroll
        for (int j = 0; j < 4; j++) acc[mi][j] = (f32x4){0.f, 0.f, 0.f, 0.f};
    for (int kc0 = 0; kc0 < 768; kc0 += 64) {
        int sA = kc0 >> 8, kd0 = kc0 & 255;
        const bf16* Asrc = proc + ((size_t)(sA * NB + b) * NN + nbase) * ND + kd0;
        __syncthreads();
        #pragma unroll
        for (int i = 0; i < 4; i++) {
            int li = i * 256 + t;
            int row = li >> 3, col = (li & 7) * 8;
            *(uint4*)&As[row * 72 + col] = *(const uint4*)(Asrc + (size_t)row * ND + col);
        }
        #pragma unroll
        for (int i = 0; i < 2; i++) {
            int li = i * 256 + t;
            int row = li >> 3, col = (li & 7) * 8;
            *(uint4*)&Bs[row * 72 + col] =
                *(const uint4*)(proj_w + (size_t)(e0 + row) * 768 + kc0 + col);
        }
        __syncthreads();
        #pragma unroll
        for (int kc = 0; kc < 64; kc += 32) {
            bf16x8 af[2], bf[4];
            #pragma unroll
            for (int mi = 0; mi < 2; mi++)
                af[mi] = *(const bf16x8*)&As[(w * 32 + mi * 16 + lan) * 72 + kc + quad * 8];
            #pragma unroll
            for (int j = 0; j < 4; j++)
                bf[j] = *(const bf16x8*)&Bs[(j * 16 + lan) * 72 + kc + quad * 8];
            #pragma unroll
            for (int mi = 0; mi < 2; mi++)
                #pragma unroll
                for (int j = 0; j < 4; j++)
                    acc[mi][j] = __builtin_amdgcn_mfma_f32_16x16x32_bf16(af[mi], bf[j], acc[mi][j], 0, 0, 0);
        }
    }
    float c0 = coeffs[b * 3], c1 = coeffs[b * 3 + 1], c2 = coeffs[b * 3 + 2];
    int f = flag[0];
    #pragma unroll
    for (int mi = 0; mi < 2; mi++) {
        #pragma unroll
        for (int j = 0; j < 4; j++) {
            int e = e0 + j * 16 + lan;
            float pb = b2f(proj_b[e]);
            #pragma unroll
            for (int r = 0; r < 4; r++) {
                int m = m0 + w * 32 + mi * 16 + quad * 4 + r;
                int n = m & (NN - 1);
                size_t pbase = ((size_t)b * NN + n) * ND + e;
                float wres = c0 * b2f(proc[pbase])
                           + c1 * b2f(proc[pbase + (size_t)1 * NB * NN * ND])
                           + c2 * b2f(proc[pbase + (size_t)2 * NB * NN * ND]);
                float v = acc[mi][j][r] + pb + wres;
                if (f) ((float*)out)[(size_t)m * ND + e] = v;
                else   ((bf16*)out)[(size_t)m * ND + e] = __float2bfloat16(v);
            }
        }
    }
}

extern "C" void kernel_launch(void* const* d_in, const int* in_sizes, int n_in,
                              void* d_out, int out_size, void* d_ws, size_t ws_size,
                              hipStream_t stream)
{
    // ---- workspace layout (bytes), total ~103.3 MB ----
    char* w8 = (char*)d_ws;
    int*   flagp   = (int*)(w8);                    // flag[0]=dtype, flag[1]=ticket
    bf16*  cvt     = (bf16*)(w8 + 16);              // 9,710,144 B
    bf16*  xn      = (bf16*)(w8 + 9710160);         // 6,291,456 B (xn -> proc)
    bf16*  xcb     = (bf16*)(w8 + 16001616);        // 12,582,912 B (y)
    bf16*  zb      = (bf16*)(w8 + 28584528);
    bf16*  xab     = (bf16*)(w8 + 41167440);
    bf16*  dtb     = (bf16*)(w8 + 53750352);
    float* xdblb   = (float*)(w8 + 66333264);       // 2,359,296 B
    float* pooledb = (float*)(w8 + 68692560);       // 6,144 B
    float* coeffsb = (float*)(w8 + 68698704);       // 32 B
    float* Hendb   = (float*)(w8 + 68698736);       // 12,582,912 B
    float* Pprodb  = (float*)(w8 + 81281648);       // 12,582,912 B
    float* xpartb  = (float*)(w8 + 93864560);       // 9,437,184 B -> end 103,301,744
    bf16*  procb   = xn;                            // proc after scan2 completes

    const bf16* c_edge   = cvt + 0;
    const bf16* c_blob   = cvt + 1048576;
    const bf16* c_spec   = cvt + 2097152;
    const bf16* c_inw    = cvt + 3145728;
    const bf16* c_outw   = cvt + 3932160;
    const bf16* c_xpw    = cvt + 4325376;
    const bf16* c_dtw    = cvt + 4399104;
    const bf16* c_alog   = cvt + 4423680;
    const bf16* c_agg1   = cvt + 4448256;
    const bf16* c_prjw   = cvt + 4644864;
    const bf16* c_convw  = cvt + 4841472;
    const bf16* c_convb  = cvt + 4849152;
    const bf16* c_dtb    = cvt + 4850688;
    const bf16* c_dp     = cvt + 4852224;
    const bf16* c_agb1   = cvt + 4853760;
    const bf16* c_agw2   = cvt + 4854016;
    const bf16* c_agb2   = cvt + 4854784;
    const bf16* c_prjb   = cvt + 4854800;
    const bf16* c_temp   = cvt + 4855056;

    CvtArgs ca;
    for (int i = 0; i < 21; i++) ca.s[i] = d_in[i];
    k_convert<<<(1709316 + 255) / 256, 256, 0, stream>>>(ca, flagp, cvt, pooledb);
    k_ln<<<6 * NN, 256, 0, stream>>>(d_in[0], d_in[1], d_in[2], d_in[3], d_in[4],
                                     cvt, xn);
    k_inproj_t<<<96 * 8, 256, 0, stream>>>(xn, c_inw, c_convw, c_convb, xab, zb);
    k_xproj_t<<<192 * 4, 256, 0, stream>>>(xab, c_xpw, xpartb);
    k_dt2<<<3072, 256, 0, stream>>>(xpartb, c_dtw, c_dtb, xdblb, dtb);
    k_scan1<<<6 * NCH * 2, 256, 0, stream>>>(dtb, xab, c_alog, xdblb, Hendb, Pprodb);
    k_scomb<<<192, 256, 0, stream>>>(Hendb, Pprodb);
    k_scan2<<<6 * NCH * 2, 256, 0, stream>>>(dtb, xab, zb, xdblb, c_alog, c_dp, Hendb, xcb);
    k_outproj_t<<<96 * 4, 256, 0, stream>>>(xcb, c_outw, c_edge, c_blob, c_spec, procb, pooledb,
                                            c_agg1, c_agb1, c_agw2, c_agb2, c_temp, coeffsb, flagp);
    k_final_t<<<32 * 4, 256, 0, stream>>>(procb, c_prjw, c_prjb, coeffsb, flagp, d_out);
}

// Round 13
// 350.309 us; speedup vs baseline: 1.0769x; 1.0769x over previous
//
#include <hip/hip_runtime.h>
#include <hip/hip_bf16.h>

#define NB 2
#define NN 2048
#define ND 256
#define NS 16
#define NDC 4
#define NDI 512
#define NDTR 16
#define LCH 32    // chunk length for parallel scan
#define NCH 64    // number of chunks (LCH*NCH == NN)

typedef __hip_bfloat16 bf16;
typedef __attribute__((ext_vector_type(8))) __bf16 bf16x8;
typedef __attribute__((ext_vector_type(4))) float f32x4;

__device__ __forceinline__ float b2f(bf16 h) { return __bfloat162float(h); }

__device__ __forceinline__ void dec8(const uint4 u, float w[8]) {
    union { unsigned u; float f; } c;
    c.u = u.x << 16;          w[0] = c.f;
    c.u = u.x & 0xffff0000u;  w[1] = c.f;
    c.u = u.y << 16;          w[2] = c.f;
    c.u = u.y & 0xffff0000u;  w[3] = c.f;
    c.u = u.z << 16;          w[4] = c.f;
    c.u = u.z & 0xffff0000u;  w[5] = c.f;
    c.u = u.w << 16;          w[6] = c.f;
    c.u = u.w & 0xffff0000u;  w[7] = c.f;
}

// ---------------- K0: convert/copy WEIGHT inputs to bf16 + flag + zero pooled ----------------
struct CvtArgs { const void* s[21]; };
__device__ __constant__ const int seg_cum[22] = {
    0, 1048576, 2097152, 3145728, 3146496, 3147264, 3933696, 3939840,
    3941376, 4015104, 4039680, 4041216, 4065792, 4067328, 4460544, 4460545,
    4657153, 4657409, 4658177, 4658180, 4854788, 4855044 };
__device__ __constant__ const int seg_dst[21] = {
    0,        1048576,  2097152,  4847616, 4848384, 3145728, 4841472, 4849152, 4325376,
    4399104,  4850688,  4423680,  4852224, 3932160, 4855056, 4448256, 4853760, 4854016,
    4854784,  4644864,  4854800 };

__global__ __launch_bounds__(256) void k_convert(CvtArgs a, int* __restrict__ flag,
                                                 bf16* __restrict__ dst,
                                                 float* __restrict__ pooled)
{
    int idx0 = blockIdx.x * 256 + threadIdx.x;
    unsigned v0 = ((const unsigned*)a.s[3])[0];
    int f = ((v0 & 0xFFFFu) == 0u) ? 1 : 0;
    if (idx0 == 0) flag[0] = f;
    if (idx0 < 1536) pooled[idx0] = 0.0f;
    int idx = idx0 + 3145728;              // features handled by k_ln
    if (idx >= 4855044) return;
    int seg = 3;
    #pragma unroll
    for (int i = 4; i < 21; i++) if (idx >= seg_cum[i]) seg = i;
    int off = idx - seg_cum[seg];
    bf16 v;
    if (f) v = __float2bfloat16(((const float*)a.s[seg])[off]);
    else   v = ((const bf16*)a.s[seg])[off];
    dst[seg_dst[seg] + off] = v;
}

// ---------------- K1: layernorm + feature conversion (reads raw inputs) ----------------
__global__ __launch_bounds__(256) void k_ln(
    const void* __restrict__ e, const void* __restrict__ bl, const void* __restrict__ sp,
    const void* __restrict__ nw_raw, const void* __restrict__ nb_raw,
    bf16* __restrict__ cvt_in, bf16* __restrict__ xn)
{
    int row = blockIdx.x;            // sb*NN + n, sb = s*NB + b
    int sb = row >> 11, n = row & (NN - 1);
    int s = sb >> 1, b = sb & 1;
    int t = threadIdx.x;
    unsigned v0 = ((const unsigned*)nw_raw)[0];
    int f = ((v0 & 0xFFFFu) == 0u);
    const void* xin = (s == 0) ? e : ((s == 1) ? bl : sp);
    size_t gi = ((size_t)(b << 11) + n) * ND + t;
    float v = f ? ((const float*)xin)[gi] : b2f(((const bf16*)xin)[gi]);
    cvt_in[(size_t)s * 1048576 + gi] = __float2bfloat16(v);
    float s1 = v, s2 = v * v;
    #pragma unroll
    for (int m = 1; m < 64; m <<= 1) { s1 += __shfl_xor(s1, m); s2 += __shfl_xor(s2, m); }
    __shared__ float r1[4], r2[4];
    int w = t >> 6;
    if ((t & 63) == 0) { r1[w] = s1; r2[w] = s2; }
    __syncthreads();
    float mean = (r1[0] + r1[1] + r1[2] + r1[3]) * (1.0f / ND);
    float ms   = (r2[0] + r2[1] + r2[2] + r2[3]) * (1.0f / ND);
    float inv = rsqrtf(ms - mean * mean + 1e-5f);
    float wv = f ? ((const float*)nw_raw)[s * ND + t] : b2f(((const bf16*)nw_raw)[s * ND + t]);
    float bv = f ? ((const float*)nb_raw)[s * ND + t] : b2f(((const bf16*)nb_raw)[s * ND + t]);
    xn[(size_t)row * ND + t] = __float2bfloat16((v - mean) * inv * wv + bv);
}

// ---------------- K2: in_proj MFMA 128x128 + FUSED causal conv + silu ----------------
__global__ __launch_bounds__(256) void k_inproj_t(
    const bf16* __restrict__ xn, const bf16* __restrict__ in_w,
    const bf16* __restrict__ conv_w, const bf16* __restrict__ conv_b,
    bf16* __restrict__ xa, bf16* __restrict__ z)
{
    __shared__ bf16 sh[2 * 128 * 72];     // As | Bs, reused as conv tile T[131][136]
    __shared__ bf16 xnx[4][72];
    bf16* As = sh;
    bf16* Bs = sh + 128 * 72;
    int bid = blockIdx.x;
    int bm = bid >> 3, bn = bid & 7;           // 96 x 8
    int m0 = bm * 128, e0 = bn * 128;
    int s = m0 >> 12;
    int nn0 = m0 & (NN - 1);
    bool doConv  = (bn < 4);
    bool doExtra = doConv && (nn0 != 0);
    const bf16* W = in_w + (size_t)s * (2 * NDI) * ND;
    int t = threadIdx.x;
    int w = t >> 6, l = t & 63;
    int wm = w >> 1, wn = w & 1;
    int quad = l >> 4, lan = l & 15;
    f32x4 acc[4][4];
    #pragma unroll
    for (int mi = 0; mi < 4; mi++)
        #pragma unroll
        for (int j = 0; j < 4; j++) acc[mi][j] = (f32x4){0.f, 0.f, 0.f, 0.f};
    f32x4 accx[4];
    #pragma unroll
    for (int j = 0; j < 4; j++) accx[j] = (f32x4){0.f, 0.f, 0.f, 0.f};
    for (int kc0 = 0; kc0 < 256; kc0 += 64) {
        __syncthreads();
        #pragma unroll
        for (int i = 0; i < 4; i++) {
            int li = i * 256 + t;
            int row = li >> 3, col = (li & 7) * 8;
            *(uint4*)&As[row * 72 + col] =
                *(const uint4*)(xn + (size_t)(m0 + row) * ND + kc0 + col);
        }
        #pragma unroll
        for (int i = 0; i < 4; i++) {
            int li = i * 256 + t;
            int row = li >> 3, col = (li & 7) * 8;
            *(uint4*)&Bs[row * 72 + col] =
                *(const uint4*)(W + (size_t)(e0 + row) * ND + kc0 + col);
        }
        if (doExtra && t < 24) {
            int i = t >> 3, q = t & 7;
            *(uint4*)&xnx[i][q * 8] =
                *(const uint4*)(xn + (size_t)(m0 - 3 + i) * ND + kc0 + q * 8);
        }
        __syncthreads();
        #pragma unroll
        for (int kc = 0; kc < 64; kc += 32) {
            bf16x8 af[4], bf[4];
            #pragma unroll
            for (int mi = 0; mi < 4; mi++)
                af[mi] = *(const bf16x8*)&As[(wm * 64 + mi * 16 + lan) * 72 + kc + quad * 8];
            #pragma unroll
            for (int j = 0; j < 4; j++)
                bf[j] = *(const bf16x8*)&Bs[(wn * 64 + j * 16 + lan) * 72 + kc + quad * 8];
            #pragma unroll
            for (int mi = 0; mi < 4; mi++)
                #pragma unroll
                for (int j = 0; j < 4; j++)
                    acc[mi][j] = __builtin_amdgcn_mfma_f32_16x16x32_bf16(af[mi], bf[j], acc[mi][j], 0, 0, 0);
            if (doExtra && wm == 0) {
                bf16x8 ax = *(const bf16x8*)&xnx[lan & 3][kc + quad * 8];
                #pragma unroll
                for (int j = 0; j < 4; j++)
                    accx[j] = __builtin_amdgcn_mfma_f32_16x16x32_bf16(ax, bf[j], accx[j], 0, 0, 0);
            }
        }
    }
    __syncthreads();   // all LDS reads done; sh reusable
    if (!doConv) {
        int ebase = e0 & (NDI - 1);
        #pragma unroll
        for (int mi = 0; mi < 4; mi++) {
            #pragma unroll
            for (int j = 0; j < 4; j++) {
                int ec = ebase + wn * 64 + j * 16 + lan;
                #pragma unroll
                for (int r = 0; r < 4; r++) {
                    int m = m0 + wm * 64 + mi * 16 + quad * 4 + r;
                    z[(size_t)m * NDI + ec] = __float2bfloat16(acc[mi][j][r]);
                }
            }
        }
        return;
    }
    // conv path: spill pre-activation tile T[131][136]
    bf16* T = sh;
    #pragma unroll
    for (int mi = 0; mi < 4; mi++) {
        #pragma unroll
        for (int j = 0; j < 4; j++) {
            int el = wn * 64 + j * 16 + lan;
            #pragma unroll
            for (int r = 0; r < 4; r++) {
                int lm = wm * 64 + mi * 16 + quad * 4 + r;
                T[(3 + lm) * 136 + el] = __float2bfloat16(acc[mi][j][r]);
            }
        }
    }
    if (wm == 0 && quad == 0) {
        #pragma unroll
        for (int j = 0; j < 4; j++) {
            int el = wn * 64 + j * 16 + lan;
            #pragma unroll
            for (int r = 0; r < 3; r++)
                T[r * 136 + el] = doExtra ? __float2bfloat16(accx[j][r]) : __float2bfloat16(0.0f);
        }
    }
    __syncthreads();
    int cg = t & 15;
    int col8 = cg * 8;
    int d8 = e0 + col8;
    const uint4* cwp = (const uint4*)(conv_w + ((size_t)s * NDI + d8) * NDC);
    float cwf[32];
    dec8(cwp[0], cwf); dec8(cwp[1], cwf + 8); dec8(cwp[2], cwf + 16); dec8(cwp[3], cwf + 24);
    float bias[8];
    dec8(*(const uint4*)(conv_b + (size_t)s * NDI + d8), bias);
    #pragma unroll
    for (int i = 0; i < 8; i++) {
        int ro = i * 16 + (t >> 4);
        float x0[8], x1[8], x2[8], x3[8];
        dec8(*(const uint4*)&T[(ro + 0) * 136 + col8], x0);
        dec8(*(const uint4*)&T[(ro + 1) * 136 + col8], x1);
        dec8(*(const uint4*)&T[(ro + 2) * 136 + col8], x2);
        dec8(*(const uint4*)&T[(ro + 3) * 136 + col8], x3);
        union { bf16 h[8]; uint4 u; } o;
        #pragma unroll
        for (int jj = 0; jj < 8; jj++) {
            float a = bias[jj] + cwf[jj * 4 + 0] * x0[jj] + cwf[jj * 4 + 1] * x1[jj]
                    + cwf[jj * 4 + 2] * x2[jj] + cwf[jj * 4 + 3] * x3[jj];
            a = a / (1.0f + __expf(-a));
            o.h[jj] = __float2bfloat16(a);
        }
        *(uint4*)(xa + (size_t)(m0 + ro) * NDI + d8) = o.u;
    }
}

// ---------------- K4a: x_proj MFMA, split-K x4 -> xpart[4][12288][48] fp32 ----------------
__global__ __launch_bounds__(256) void k_xproj_t(
    const bf16* __restrict__ xa, const bf16* __restrict__ xproj_w,
    float* __restrict__ xpart)
{
    __shared__ bf16 As[64 * 72];
    __shared__ bf16 Bs[48 * 72];
    int bid = blockIdx.x;
    int bm = bid >> 2, ks = bid & 3;       // 192 x 4
    int m0 = bm * 64;
    int s = m0 >> 12;
    const bf16* W = xproj_w + (size_t)s * 48 * NDI;
    int t = threadIdx.x;
    int w = t >> 6, l = t & 63;
    int quad = l >> 4, lan = l & 15;
    f32x4 acc[3];
    #pragma unroll
    for (int j = 0; j < 3; j++) acc[j] = (f32x4){0.f, 0.f, 0.f, 0.f};
    for (int kc0 = ks * 128; kc0 < ks * 128 + 128; kc0 += 64) {
        __syncthreads();
        #pragma unroll
        for (int i = 0; i < 2; i++) {
            int li = i * 256 + t;
            int row = li >> 3, col = (li & 7) * 8;
            *(uint4*)&As[row * 72 + col] =
                *(const uint4*)(xa + (size_t)(m0 + row) * NDI + kc0 + col);
        }
        {
            int li = t;
            if (li < 384) {
                int row = li >> 3, col = (li & 7) * 8;
                *(uint4*)&Bs[row * 72 + col] =
                    *(const uint4*)(W + (size_t)row * NDI + kc0 + col);
            }
            int li2 = 256 + t;
            if (li2 < 384) {
                int row = li2 >> 3, col = (li2 & 7) * 8;
                *(uint4*)&Bs[row * 72 + col] =
                    *(const uint4*)(W + (size_t)row * NDI + kc0 + col);
            }
        }
        __syncthreads();
        #pragma unroll
        for (int kc = 0; kc < 64; kc += 32) {
            bf16x8 af = *(const bf16x8*)&As[(w * 16 + lan) * 72 + kc + quad * 8];
            #pragma unroll
            for (int j = 0; j < 3; j++) {
                bf16x8 bf = *(const bf16x8*)&Bs[(j * 16 + lan) * 72 + kc + quad * 8];
                acc[j] = __builtin_amdgcn_mfma_f32_16x16x32_bf16(af, bf, acc[j], 0, 0, 0);
            }
        }
    }
    float* dst = xpart + (size_t)ks * (12288 * 48);
    #pragma unroll
    for (int j = 0; j < 3; j++) {
        int e = j * 16 + lan;
        #pragma unroll
        for (int r = 0; r < 4; r++) {
            int m = m0 + w * 16 + quad * 4 + r;
            dst[(size_t)m * 48 + e] = acc[j][r];
        }
    }
}

// ---------------- K4b: reduce split-K + dt GEMM (K=16) + softplus ----------------
__global__ __launch_bounds__(256) void k_dt2(
    const float* __restrict__ xpart, const bf16* __restrict__ dt_w,
    const bf16* __restrict__ dt_b, float* __restrict__ xdbl, bf16* __restrict__ dt)
{
    __shared__ float xs[4][48];
    int row0 = blockIdx.x * 4;
    int s = row0 >> 12;
    int t = threadIdx.x;
    if (t < 192) {
        int r = t / 48, e = t % 48;
        size_t base = (size_t)(row0 + r) * 48 + e;
        const size_t seg = (size_t)12288 * 48;
        float v = xpart[base] + xpart[base + seg] + xpart[base + 2 * seg] + xpart[base + 3 * seg];
        xs[r][e] = v;
        if (e >= 16) xdbl[base] = v;    // B and C columns for the scans
    }
    __syncthreads();
    #pragma unroll
    for (int dd = 0; dd < 2; dd++) {
        int d = t + dd * 256;
        const uint4* wp = (const uint4*)(dt_w + ((size_t)s * NDI + d) * NDTR);
        float w[16]; dec8(wp[0], w); dec8(wp[1], w + 8);
        float bias = b2f(dt_b[s * NDI + d]);
        #pragma unroll
        for (int r = 0; r < 4; r++) {
            float a = bias;
            #pragma unroll
            for (int j = 0; j < 16; j++) a += w[j] * xs[r][j];
            a = (a > 20.0f) ? a : log1pf(__expf(a));   // softplus
            dt[(size_t)(row0 + r) * NDI + d] = __float2bfloat16(a);
        }
    }
}

// ---------------- K5a: chunk-local scan (LDS-staged) -> Hend, Pprod ----------------
__global__ __launch_bounds__(256) void k_scan1(
    const bf16* __restrict__ dt, const bf16* __restrict__ xa,
    const bf16* __restrict__ A_log, const float* __restrict__ xdbl,
    float* __restrict__ Hend, float* __restrict__ Pprod)
{
    __shared__ bf16 dts[LCH * 256];
    __shared__ bf16 xas[LCH * 256];
    __shared__ float Bs[LCH * NS];
    int bid = blockIdx.x;                 // 6 * NCH * 2 = 768
    int sb = bid / (NCH * 2);
    int rem = bid % (NCH * 2);
    int chunk = rem >> 1, dg = rem & 1;
    int s = sb >> 1;
    int t = threadIdx.x;
    int d = dg * 256 + t;
    int n0 = chunk * LCH;
    size_t rowbase = (size_t)sb * NN;
    const bf16* dtg = dt + (rowbase + n0) * NDI + dg * 256;
    const bf16* xag = xa + (rowbase + n0) * NDI + dg * 256;
    #pragma unroll
    for (int i = 0; i < 4; i++) {
        int li = i * 256 + t;
        int row = li >> 5, q = li & 31;
        ((uint4*)dts)[li] = *(const uint4*)(dtg + (size_t)row * NDI + q * 8);
        ((uint4*)xas)[li] = *(const uint4*)(xag + (size_t)row * NDI + q * 8);
    }
    if (t < 128) {
        int row = t >> 2, q = t & 3;
        ((float4*)Bs)[t] = ((const float4*)(xdbl + (rowbase + n0 + row) * 48 + 16))[q];
    }
    float A[16];
    {
        const uint4* ap = (const uint4*)(A_log + ((size_t)s * NDI + d) * NS);
        float al[8]; dec8(ap[0], al);
        #pragma unroll
        for (int i = 0; i < 8; i++) A[i] = -__expf(al[i]);
        dec8(ap[1], al);
        #pragma unroll
        for (int i = 0; i < 8; i++) A[8 + i] = -__expf(al[i]);
    }
    __syncthreads();
    float h[16], P[16];
    #pragma unroll
    for (int i = 0; i < 16; i++) { h[i] = 0.0f; P[i] = 1.0f; }
    #pragma unroll 4
    for (int nl = 0; nl < LCH; nl++) {
        float dtv = b2f(dts[nl * 256 + t]);
        float xav = b2f(xas[nl * 256 + t]);
        float bcom = dtv * xav;
        const float4* br = (const float4*)&Bs[nl * NS];
        float4 b0 = br[0], b1 = br[1], b2 = br[2], b3 = br[3];
        float bv[16] = {b0.x,b0.y,b0.z,b0.w,b1.x,b1.y,b1.z,b1.w,
                        b2.x,b2.y,b2.z,b2.w,b3.x,b3.y,b3.z,b3.w};
        #pragma unroll
        for (int st = 0; st < 16; st++) {
            float dA = __expf(dtv * A[st]);
            h[st] = dA * h[st] + bcom * bv[st];
            P[st] *= dA;
        }
    }
    size_t base = ((size_t)(chunk * 6 + sb) * NS) * NDI + d;
    #pragma unroll
    for (int st = 0; st < 16; st++) {
        Hend[base + (size_t)st * NDI] = h[st];
        Pprod[base + (size_t)st * NDI] = P[st];
    }
}

// ---------------- K5b: prefix over chunk summaries, parallel over states ----------------
__global__ __launch_bounds__(256) void k_scomb(float* __restrict__ Hend, const float* __restrict__ Pprod)
{
    int idx = blockIdx.x * 256 + threadIdx.x;   // 49152 = 6 sb * 16 st * 512 d
    int sb = idx >> 13;
    int rem = idx & 8191;
    int st = rem >> 9, d = rem & 511;
    float h = 0.0f;
    const size_t stride = (size_t)6 * NS * NDI;
    size_t g = ((size_t)sb * NS + st) * NDI + d;
    #pragma unroll 4
    for (int c = 0; c < NCH; c++) {
        float He = Hend[g], Pp = Pprod[g];
        Hend[g] = h;                 // h_start for this chunk
        h = He + Pp * h;
        g += stride;
    }
}

// ---------------- K5c: re-scan chunks from h_start (LDS-staged), C-dot + gating -> y ----------------
__global__ __launch_bounds__(256) void k_scan2(
    const bf16* __restrict__ dt, const bf16* __restrict__ xa, const bf16* __restrict__ z,
    const float* __restrict__ xdbl,
    const bf16* __restrict__ A_log, const bf16* __restrict__ Dp,
    const float* __restrict__ Hstart, bf16* __restrict__ y)
{
    __shared__ bf16 dts[LCH * 256];
    __shared__ bf16 xas[LCH * 256];
    __shared__ bf16 zs[LCH * 256];
    __shared__ float Bs[LCH * NS], Cs[LCH * NS];
    int bid = blockIdx.x;
    int sb = bid / (NCH * 2);
    int rem = bid % (NCH * 2);
    int chunk = rem >> 1, dg = rem & 1;
    int s = sb >> 1;
    int t = threadIdx.x;
    int d = dg * 256 + t;
    int n0 = chunk * LCH;
    size_t rowbase = (size_t)sb * NN;
    const bf16* dtg = dt + (rowbase + n0) * NDI + dg * 256;
    const bf16* xag = xa + (rowbase + n0) * NDI + dg * 256;
    const bf16* zg  = z  + (rowbase + n0) * NDI + dg * 256;
    #pragma unroll
    for (int i = 0; i < 4; i++) {
        int li = i * 256 + t;
        int row = li >> 5, q = li & 31;
        ((uint4*)dts)[li] = *(const uint4*)(dtg + (size_t)row * NDI + q * 8);
        ((uint4*)xas)[li] = *(const uint4*)(xag + (size_t)row * NDI + q * 8);
        ((uint4*)zs)[li]  = *(const uint4*)(zg  + (size_t)row * NDI + q * 8);
    }
    if (t < 128) {
        int row = t >> 2, q = t & 3;
        ((float4*)Bs)[t] = ((const float4*)(xdbl + (rowbase + n0 + row) * 48 + 16))[q];
    } else {
        int t2 = t - 128;
        int row = t2 >> 2, q = t2 & 3;
        ((float4*)Cs)[t2] = ((const float4*)(xdbl + (rowbase + n0 + row) * 48 + 32))[q];
    }
    float A[16];
    {
        const uint4* ap = (const uint4*)(A_log + ((size_t)s * NDI + d) * NS);
        float al[8]; dec8(ap[0], al);
        #pragma unroll
        for (int i = 0; i < 8; i++) A[i] = -__expf(al[i]);
        dec8(ap[1], al);
        #pragma unroll
        for (int i = 0; i < 8; i++) A[8 + i] = -__expf(al[i]);
    }
    float Dpv = b2f(Dp[s * NDI + d]);
    float h[16];
    {
        size_t base = ((size_t)(chunk * 6 + sb) * NS) * NDI + d;
        #pragma unroll
        for (int st = 0; st < 16; st++) h[st] = Hstart[base + (size_t)st * NDI];
    }
    __syncthreads();
    bf16* yp = y + (rowbase + n0) * NDI + d;
    #pragma unroll 4
    for (int nl = 0; nl < LCH; nl++) {
        float dtv = b2f(dts[nl * 256 + t]);
        float xav = b2f(xas[nl * 256 + t]);
        float zz  = b2f(zs[nl * 256 + t]);
        float bcom = dtv * xav;
        const float4* br = (const float4*)&Bs[nl * NS];
        const float4* cr = (const float4*)&Cs[nl * NS];
        float4 b0 = br[0], b1 = br[1], b2 = br[2], b3 = br[3];
        float4 c0 = cr[0], c1 = cr[1], c2 = cr[2], c3 = cr[3];
        float bv[16] = {b0.x,b0.y,b0.z,b0.w,b1.x,b1.y,b1.z,b1.w,
                        b2.x,b2.y,b2.z,b2.w,b3.x,b3.y,b3.z,b3.w};
        float cv[16] = {c0.x,c0.y,c0.z,c0.w,c1.x,c1.y,c1.z,c1.w,
                        c2.x,c2.y,c2.z,c2.w,c3.x,c3.y,c3.z,c3.w};
        float yacc = 0.0f;
        #pragma unroll
        for (int st = 0; st < 16; st++) {
            float dA = __expf(dtv * A[st]);
            h[st] = dA * h[st] + bcom * bv[st];
            yacc += h[st] * cv[st];
        }
        float yv = yacc + xav * Dpv;
        yv *= zz / (1.0f + __expf(-zz));
        yp[(size_t)nl * NDI] = __float2bfloat16(yv);
    }
}

// ---------------- K6: out_proj tiled MFMA + residual -> proc, fused pooling ----------------
__global__ __launch_bounds__(256) void k_outproj_t(
    const bf16* __restrict__ y, const bf16* __restrict__ out_w,
    const bf16* __restrict__ e_, const bf16* __restrict__ bl, const bf16* __restrict__ sp,
    bf16* __restrict__ proc, float* __restrict__ pooled)
{
    __shared__ bf16 As[128 * 72];
    __shared__ bf16 Bs[64 * 72];
    __shared__ float colsum[64];
    int bid = blockIdx.x;
    int bm = bid >> 2, bn = bid & 3;
    int m0 = bm * 128, e0 = bn * 64;
    int s = m0 >> 12;
    const bf16* W = out_w + (size_t)s * ND * NDI;
    int t = threadIdx.x;
    int w = t >> 6, l = t & 63;
    int quad = l >> 4, lan = l & 15;
    f32x4 acc[2][4];
    #pragma unroll
    for (int mi = 0; mi < 2; mi++)
        #pragma unroll
        for (int j = 0; j < 4; j++) acc[mi][j] = (f32x4){0.f, 0.f, 0.f, 0.f};
    for (int kc0 = 0; kc0 < 512; kc0 += 64) {
        __syncthreads();
        #pragma unroll
        for (int i = 0; i < 4; i++) {
            int li = i * 256 + t;
            int row = li >> 3, col = (li & 7) * 8;
            *(uint4*)&As[row * 72 + col] =
                *(const uint4*)(y + (size_t)(m0 + row) * NDI + kc0 + col);
        }
        #pragma unroll
        for (int i = 0; i < 2; i++) {
            int li = i * 256 + t;
            int row = li >> 3, col = (li & 7) * 8;
            *(uint4*)&Bs[row * 72 + col] =
                *(const uint4*)(W + (size_t)(e0 + row) * NDI + kc0 + col);
        }
        __syncthreads();
        #pragma unroll
        for (int kc = 0; kc < 64; kc += 32) {
            bf16x8 af[2], bf[4];
            #pragma unroll
            for (int mi = 0; mi < 2; mi++)
                af[mi] = *(const bf16x8*)&As[(w * 32 + mi * 16 + lan) * 72 + kc + quad * 8];
            #pragma unroll
            for (int j = 0; j < 4; j++)
                bf[j] = *(const bf16x8*)&Bs[(j * 16 + lan) * 72 + kc + quad * 8];
            #pragma unroll
            for (int mi = 0; mi < 2; mi++)
                #pragma unroll
                for (int j = 0; j < 4; j++)
                    acc[mi][j] = __builtin_amdgcn_mfma_f32_16x16x32_bf16(af[mi], bf[j], acc[mi][j], 0, 0, 0);
        }
    }
    if (t < 64) colsum[t] = 0.0f;
    __syncthreads();
    const bf16* xin = (s == 0) ? e_ : ((s == 1) ? bl : sp);
    int b = (m0 >> 11) & 1;
    #pragma unroll
    for (int mi = 0; mi < 2; mi++) {
        #pragma unroll
        for (int j = 0; j < 4; j++) {
            int e = e0 + j * 16 + lan;
            float ps = 0.0f;
            #pragma unroll
            for (int r = 0; r < 4; r++) {
                int m = m0 + w * 32 + mi * 16 + quad * 4 + r;
                int n = m & (NN - 1);
                float v = acc[mi][j][r] + b2f(xin[((size_t)(b * NN + n)) * ND + e]);
                proc[(size_t)m * ND + e] = __float2bfloat16(v);
                ps += v;
            }
            atomicAdd(&colsum[j * 16 + lan], ps);
        }
    }
    __syncthreads();
    if (t < 64) atomicAdd(&pooled[b * 768 + s * 256 + e0 + t], colsum[t]);
}

// ---------------- K8: gelu MLP + double softmax -> coeffs (B,3) fp32 ----------------
__global__ __launch_bounds__(256) void k_coeff(
    const float* __restrict__ pooled,
    const bf16* __restrict__ agg_w1, const bf16* __restrict__ agg_b1,
    const bf16* __restrict__ agg_w2, const bf16* __restrict__ agg_b2,
    const bf16* __restrict__ temp, float* __restrict__ coeffs)
{
    __shared__ float hb[256];
    __shared__ float lg[3];
    int t = threadIdx.x;
    for (int b = 0; b < NB; b++) {
        float dot = 0.0f;
        const uint4* wp = (const uint4*)(agg_w1 + (size_t)t * 768);
        for (int k8 = 0; k8 < 96; k8++) {
            float w[8]; dec8(wp[k8], w);
            const float* pp = pooled + b * 768 + k8 * 8;
            #pragma unroll
            for (int j = 0; j < 8; j++) dot += w[j] * pp[j];
        }
        float x = b2f(agg_b1[t]) + dot * (1.0f / NN);
        float inner = 0.7978845608028654f * (x + 0.044715f * x * x * x);
        hb[t] = 0.5f * x * (1.0f + tanhf(inner));
        __syncthreads();
        if (t < 3) {
            float l = b2f(agg_b2[t]);
            const bf16* w2 = agg_w2 + t * 256;
            for (int d2 = 0; d2 < 256; d2++) l += b2f(w2[d2]) * hb[d2];
            lg[t] = l;
        }
        __syncthreads();
        if (t == 0) {
            float m = fmaxf(lg[0], fmaxf(lg[1], lg[2]));
            float e0 = __expf(lg[0] - m), e1 = __expf(lg[1] - m), e2 = __expf(lg[2] - m);
            float iS = 1.0f / (e0 + e1 + e2);
            float c0 = e0 * iS, c1 = e1 * iS, c2 = e2 * iS;
            float tt = b2f(temp[0]) + 1e-6f;
            float m2 = fmaxf(c0, fmaxf(c1, c2)) / tt;
            e0 = __expf(c0 / tt - m2); e1 = __expf(c1 / tt - m2); e2 = __expf(c2 / tt - m2);
            iS = 1.0f / (e0 + e1 + e2);
            coeffs[b * 3 + 0] = e0 * iS;
            coeffs[b * 3 + 1] = e1 * iS;
            coeffs[b * 3 + 2] = e2 * iS;
        }
        __syncthreads();
    }
}

// ---------------- K9: final proj tiled MFMA + weighted residual -> d_out ----------------
__global__ __launch_bounds__(256) void k_final_t(
    const bf16* __restrict__ proc, const bf16* __restrict__ proj_w,
    const bf16* __restrict__ proj_b, const float* __restrict__ coeffs,
    const int* __restrict__ flag, void* __restrict__ out)
{
    __shared__ bf16 As[128 * 72];
    __shared__ bf16 Bs[64 * 72];
    int bid = blockIdx.x;
    int bm = bid >> 2, bn = bid & 3;
    int m0 = bm * 128, e0 = bn * 64;
    int b = m0 >> 11;                 // batch, const per block
    int nbase = m0 & (NN - 1);
    int t = threadIdx.x;
    int w = t >> 6, l = t & 63;
    int quad = l >> 4, lan = l & 15;
    f32x4 acc[2][4];
    #pragma unroll
    for (int mi = 0; mi < 2; mi++)
        #pragma unroll
        for (int j = 0; j < 4; j++) acc[mi][j] = (f32x4){0.f, 0.f, 0.f, 0.f};
    for (int kc0 = 0; kc0 < 768; kc0 += 64) {
        int sA = kc0 >> 8, kd0 = kc0 & 255;
        const bf16* Asrc = proc + ((size_t)(sA * NB + b) * NN + nbase) * ND + kd0;
        __syncthreads();
        #pragma unroll
        for (int i = 0; i < 4; i++) {
            int li = i * 256 + t;
            int row = li >> 3, col = (li & 7) * 8;
            *(uint4*)&As[row * 72 + col] = *(const uint4*)(Asrc + (size_t)row * ND + col);
        }
        #pragma unroll
        for (int i = 0; i < 2; i++) {
            int li = i * 256 + t;
            int row = li >> 3, col = (li & 7) * 8;
            *(uint4*)&Bs[row * 72 + col] =
                *(const uint4*)(proj_w + (size_t)(e0 + row) * 768 + kc0 + col);
        }
        __syncthreads();
        #pragma unroll
        for (int kc = 0; kc < 64; kc += 32) {
            bf16x8 af[2], bf[4];
            #pragma unroll
            for (int mi = 0; mi < 2; mi++)
                af[mi] = *(const bf16x8*)&As[(w * 32 + mi * 16 + lan) * 72 + kc + quad * 8];
            #pragma unroll
            for (int j = 0; j < 4; j++)
                bf[j] = *(const bf16x8*)&Bs[(j * 16 + lan) * 72 + kc + quad * 8];
            #pragma unroll
            for (int mi = 0; mi < 2; mi++)
                #pragma unroll
                for (int j = 0; j < 4; j++)
                    acc[mi][j] = __builtin_amdgcn_mfma_f32_16x16x32_bf16(af[mi], bf[j], acc[mi][j], 0, 0, 0);
        }
    }
    float c0 = coeffs[b * 3], c1 = coeffs[b * 3 + 1], c2 = coeffs[b * 3 + 2];
    int f = flag[0];
    #pragma unroll
    for (int mi = 0; mi < 2; mi++) {
        #pragma unroll
        for (int j = 0; j < 4; j++) {
            int e = e0 + j * 16 + lan;
            float pb = b2f(proj_b[e]);
            #pragma unroll
            for (int r = 0; r < 4; r++) {
                int m = m0 + w * 32 + mi * 16 + quad * 4 + r;
                int n = m & (NN - 1);
                size_t pbase = ((size_t)b * NN + n) * ND + e;
                float wres = c0 * b2f(proc[pbase])
                           + c1 * b2f(proc[pbase + (size_t)1 * NB * NN * ND])
                           + c2 * b2f(proc[pbase + (size_t)2 * NB * NN * ND]);
                float v = acc[mi][j][r] + pb + wres;
                if (f) ((float*)out)[(size_t)m * ND + e] = v;
                else   ((bf16*)out)[(size_t)m * ND + e] = __float2bfloat16(v);
            }
        }
    }
}

extern "C" void kernel_launch(void* const* d_in, const int* in_sizes, int n_in,
                              void* d_out, int out_size, void* d_ws, size_t ws_size,
                              hipStream_t stream)
{
    // ---- workspace layout (bytes), total ~103.3 MB ----
    char* w8 = (char*)d_ws;
    int*   flagp   = (int*)(w8);
    bf16*  cvt     = (bf16*)(w8 + 16);              // 9,710,144 B
    bf16*  xn      = (bf16*)(w8 + 9710160);         // 6,291,456 B (xn -> proc)
    bf16*  xcb     = (bf16*)(w8 + 16001616);        // 12,582,912 B (y)
    bf16*  zb      = (bf16*)(w8 + 28584528);
    bf16*  xab     = (bf16*)(w8 + 41167440);
    bf16*  dtb     = (bf16*)(w8 + 53750352);
    float* xdblb   = (float*)(w8 + 66333264);       // 2,359,296 B
    float* pooledb = (float*)(w8 + 68692560);       // 6,144 B
    float* coeffsb = (float*)(w8 + 68698704);       // 32 B
    float* Hendb   = (float*)(w8 + 68698736);       // 12,582,912 B
    float* Pprodb  = (float*)(w8 + 81281648);       // 12,582,912 B
    float* xpartb  = (float*)(w8 + 93864560);       // 9,437,184 B -> end 103,301,744
    bf16*  procb   = xn;                            // proc after scan2 completes

    const bf16* c_edge   = cvt + 0;
    const bf16* c_blob   = cvt + 1048576;
    const bf16* c_spec   = cvt + 2097152;
    const bf16* c_inw    = cvt + 3145728;
    const bf16* c_outw   = cvt + 3932160;
    const bf16* c_xpw    = cvt + 4325376;
    const bf16* c_dtw    = cvt + 4399104;
    const bf16* c_alog   = cvt + 4423680;
    const bf16* c_agg1   = cvt + 4448256;
    const bf16* c_prjw   = cvt + 4644864;
    const bf16* c_convw  = cvt + 4841472;
    const bf16* c_convb  = cvt + 4849152;
    const bf16* c_dtb    = cvt + 4850688;
    const bf16* c_dp     = cvt + 4852224;
    const bf16* c_agb1   = cvt + 4853760;
    const bf16* c_agw2   = cvt + 4854016;
    const bf16* c_agb2   = cvt + 4854784;
    const bf16* c_prjb   = cvt + 4854800;
    const bf16* c_temp   = cvt + 4855056;

    CvtArgs ca;
    for (int i = 0; i < 21; i++) ca.s[i] = d_in[i];
    k_convert<<<(1709316 + 255) / 256, 256, 0, stream>>>(ca, flagp, cvt, pooledb);
    k_ln<<<6 * NN, 256, 0, stream>>>(d_in[0], d_in[1], d_in[2], d_in[3], d_in[4],
                                     cvt, xn);
    k_inproj_t<<<96 * 8, 256, 0, stream>>>(xn, c_inw, c_convw, c_convb, xab, zb);
    k_xproj_t<<<192 * 4, 256, 0, stream>>>(xab, c_xpw, xpartb);
    k_dt2<<<3072, 256, 0, stream>>>(xpartb, c_dtw, c_dtb, xdblb, dtb);
    k_scan1<<<6 * NCH * 2, 256, 0, stream>>>(dtb, xab, c_alog, xdblb, Hendb, Pprodb);
    k_scomb<<<192, 256, 0, stream>>>(Hendb, Pprodb);
    k_scan2<<<6 * NCH * 2, 256, 0, stream>>>(dtb, xab, zb, xdblb, c_alog, c_dp, Hendb, xcb);
    k_outproj_t<<<96 * 4, 256, 0, stream>>>(xcb, c_outw, c_edge, c_blob, c_spec, procb, pooledb);
    k_coeff<<<1, 256, 0, stream>>>(pooledb, c_agg1, c_agb1, c_agw2, c_agb2, c_temp, coeffsb);
    k_final_t<<<32 * 4, 256, 0, stream>>>(procb, c_prjw, c_prjb, coeffsb, flagp, d_out);
}

// Round 14
// 322.667 us; speedup vs baseline: 1.1692x; 1.0857x over previous
//
#include <hip/hip_runtime.h>
#include <hip/hip_bf16.h>

#define NB 2
#define NN 2048
#define ND 256
#define NS 16
#define NDC 4
#define NDI 512
#define NDTR 16
#define LCH 32    // chunk length for parallel scan
#define NCH 64    // number of chunks (LCH*NCH == NN)

typedef __hip_bfloat16 bf16;
typedef __attribute__((ext_vector_type(8))) __bf16 bf16x8;
typedef __attribute__((ext_vector_type(4))) float f32x4;

__device__ __forceinline__ float b2f(bf16 h) { return __bfloat162float(h); }

__device__ __forceinline__ void dec8(const uint4 u, float w[8]) {
    union { unsigned u; float f; } c;
    c.u = u.x << 16;          w[0] = c.f;
    c.u = u.x & 0xffff0000u;  w[1] = c.f;
    c.u = u.y << 16;          w[2] = c.f;
    c.u = u.y & 0xffff0000u;  w[3] = c.f;
    c.u = u.z << 16;          w[4] = c.f;
    c.u = u.z & 0xffff0000u;  w[5] = c.f;
    c.u = u.w << 16;          w[6] = c.f;
    c.u = u.w & 0xffff0000u;  w[7] = c.f;
}

// ---------------- K0+K1 merged: LN+feature-convert (blocks < 12288) | weight convert (rest) ----------------
struct CvtArgs { const void* s[21]; };
__device__ __constant__ const int seg_cum[22] = {
    0, 1048576, 2097152, 3145728, 3146496, 3147264, 3933696, 3939840,
    3941376, 4015104, 4039680, 4041216, 4065792, 4067328, 4460544, 4460545,
    4657153, 4657409, 4658177, 4658180, 4854788, 4855044 };
__device__ __constant__ const int seg_dst[21] = {
    0,        1048576,  2097152,  4847616, 4848384, 3145728, 4841472, 4849152, 4325376,
    4399104,  4850688,  4423680,  4852224, 3932160, 4855056, 4448256, 4853760, 4854016,
    4854784,  4644864,  4854800 };

__global__ __launch_bounds__(256) void k_ln_cvt(
    CvtArgs a, int* __restrict__ flag,
    bf16* __restrict__ cvt, float* __restrict__ pooled, bf16* __restrict__ xn)
{
    int t = threadIdx.x;
    unsigned v0 = ((const unsigned*)a.s[3])[0];
    int f = ((v0 & 0xFFFFu) == 0u);
    if (blockIdx.x >= 12288) {
        // ---- weight conversion path ----
        int idx0 = (blockIdx.x - 12288) * 256 + t;
        if (idx0 == 0) flag[0] = f;
        if (idx0 < 1536) pooled[idx0] = 0.0f;
        int idx = idx0 + 3145728;
        if (idx >= 4855044) return;
        int seg = 3;
        #pragma unroll
        for (int i = 4; i < 21; i++) if (idx >= seg_cum[i]) seg = i;
        int off = idx - seg_cum[seg];
        bf16 v;
        if (f) v = __float2bfloat16(((const float*)a.s[seg])[off]);
        else   v = ((const bf16*)a.s[seg])[off];
        cvt[seg_dst[seg] + off] = v;
        return;
    }
    // ---- layernorm + feature conversion path ----
    int row = blockIdx.x;            // sb*NN + n, sb = s*NB + b
    int sb = row >> 11, n = row & (NN - 1);
    int s = sb >> 1, b = sb & 1;
    const void* xin = a.s[s];
    size_t gi = ((size_t)(b << 11) + n) * ND + t;
    float v = f ? ((const float*)xin)[gi] : b2f(((const bf16*)xin)[gi]);
    cvt[(size_t)s * 1048576 + gi] = __float2bfloat16(v);
    float s1 = v, s2 = v * v;
    #pragma unroll
    for (int m = 1; m < 64; m <<= 1) { s1 += __shfl_xor(s1, m); s2 += __shfl_xor(s2, m); }
    __shared__ float r1[4], r2[4];
    int w = t >> 6;
    if ((t & 63) == 0) { r1[w] = s1; r2[w] = s2; }
    __syncthreads();
    float mean = (r1[0] + r1[1] + r1[2] + r1[3]) * (1.0f / ND);
    float ms   = (r2[0] + r2[1] + r2[2] + r2[3]) * (1.0f / ND);
    float inv = rsqrtf(ms - mean * mean + 1e-5f);
    const void* nw_raw = a.s[3];
    const void* nb_raw = a.s[4];
    float wv = f ? ((const float*)nw_raw)[s * ND + t] : b2f(((const bf16*)nw_raw)[s * ND + t]);
    float bv = f ? ((const float*)nb_raw)[s * ND + t] : b2f(((const bf16*)nb_raw)[s * ND + t]);
    xn[(size_t)row * ND + t] = __float2bfloat16((v - mean) * inv * wv + bv);
}

// ---------------- K2: in_proj tiled MFMA GEMM 128x128 -> xc, z ----------------
__global__ __launch_bounds__(256) void k_inproj_t(
    const bf16* __restrict__ xn, const bf16* __restrict__ in_w,
    bf16* __restrict__ xc, bf16* __restrict__ z)
{
    __shared__ bf16 As[128 * 72];
    __shared__ bf16 Bs[128 * 72];
    int bid = blockIdx.x;
    int bm = bid >> 3, bn = bid & 7;           // 96 x 8
    int m0 = bm * 128, e0 = bn * 128;
    int s = m0 >> 12;
    const bf16* W = in_w + (size_t)s * (2 * NDI) * ND;
    int t = threadIdx.x;
    int w = t >> 6, l = t & 63;
    int wm = w >> 1, wn = w & 1;
    int quad = l >> 4, lan = l & 15;
    f32x4 acc[4][4];
    #pragma unroll
    for (int mi = 0; mi < 4; mi++)
        #pragma unroll
        for (int j = 0; j < 4; j++) acc[mi][j] = (f32x4){0.f, 0.f, 0.f, 0.f};
    for (int kc0 = 0; kc0 < 256; kc0 += 64) {
        __syncthreads();
        #pragma unroll
        for (int i = 0; i < 4; i++) {
            int li = i * 256 + t;
            int row = li >> 3, col = (li & 7) * 8;
            *(uint4*)&As[row * 72 + col] =
                *(const uint4*)(xn + (size_t)(m0 + row) * ND + kc0 + col);
        }
        #pragma unroll
        for (int i = 0; i < 4; i++) {
            int li = i * 256 + t;
            int row = li >> 3, col = (li & 7) * 8;
            *(uint4*)&Bs[row * 72 + col] =
                *(const uint4*)(W + (size_t)(e0 + row) * ND + kc0 + col);
        }
        __syncthreads();
        #pragma unroll
        for (int kc = 0; kc < 64; kc += 32) {
            bf16x8 af[4], bf[4];
            #pragma unroll
            for (int mi = 0; mi < 4; mi++)
                af[mi] = *(const bf16x8*)&As[(wm * 64 + mi * 16 + lan) * 72 + kc + quad * 8];
            #pragma unroll
            for (int j = 0; j < 4; j++)
                bf[j] = *(const bf16x8*)&Bs[(wn * 64 + j * 16 + lan) * 72 + kc + quad * 8];
            #pragma unroll
            for (int mi = 0; mi < 4; mi++)
                #pragma unroll
                for (int j = 0; j < 4; j++)
                    acc[mi][j] = __builtin_amdgcn_mfma_f32_16x16x32_bf16(af[mi], bf[j], acc[mi][j], 0, 0, 0);
        }
    }
    #pragma unroll
    for (int mi = 0; mi < 4; mi++) {
        #pragma unroll
        for (int j = 0; j < 4; j++) {
            int e = e0 + wn * 64 + j * 16 + lan;
            bf16* dst = (e < NDI) ? xc : z;
            int ec = e & (NDI - 1);
            #pragma unroll
            for (int r = 0; r < 4; r++) {
                int m = m0 + wm * 64 + mi * 16 + quad * 4 + r;
                dst[(size_t)m * NDI + ec] = __float2bfloat16(acc[mi][j][r]);
            }
        }
    }
}

// ---------------- K3: causal depthwise conv (DC=4) + silu -> xa, vectorized x8 ----------------
__global__ __launch_bounds__(256) void k_conv(
    const bf16* __restrict__ xc, const bf16* __restrict__ conv_w,
    const bf16* __restrict__ conv_b, bf16* __restrict__ xa)
{
    int idx = blockIdx.x * 256 + threadIdx.x;   // over 6*2048*512/8 = 786432
    int d8 = (idx & 63) * 8;
    int rn = idx >> 6;                          // sb*NN + n
    int n = rn & (NN - 1);
    int sb = rn >> 11;
    int s = sb >> 1;
    const uint4* cwp = (const uint4*)(conv_w + ((size_t)s * NDI + d8) * NDC);
    float cwf[32];
    dec8(cwp[0], cwf); dec8(cwp[1], cwf + 8); dec8(cwp[2], cwf + 16); dec8(cwp[3], cwf + 24);
    float bias[8];
    dec8(*(const uint4*)(conv_b + (size_t)s * NDI + d8), bias);
    size_t g = (size_t)rn * NDI + d8;
    float xv[4][8];   // xv[tau] = x[n-tau]
    #pragma unroll
    for (int tau = 0; tau < 4; tau++) {
        if (n >= tau) dec8(*(const uint4*)(xc + g - (size_t)tau * NDI), xv[tau]);
        else
            #pragma unroll
            for (int j = 0; j < 8; j++) xv[tau][j] = 0.0f;
    }
    union { bf16 h[8]; uint4 u; } o;
    #pragma unroll
    for (int j = 0; j < 8; j++) {
        float a = bias[j];
        #pragma unroll
        for (int k = 0; k < 4; k++) a += cwf[j * 4 + k] * xv[3 - k][j];
        a = a / (1.0f + __expf(-a));
        o.h[j] = __float2bfloat16(a);
    }
    *(uint4*)(xa + g) = o.u;
}

// ---------------- K4a: x_proj MFMA, split-K x4 -> xpart[4][12288][48] fp32 ----------------
__global__ __launch_bounds__(256) void k_xproj_t(
    const bf16* __restrict__ xa, const bf16* __restrict__ xproj_w,
    float* __restrict__ xpart)
{
    __shared__ bf16 As[64 * 72];
    __shared__ bf16 Bs[48 * 72];
    int bid = blockIdx.x;
    int bm = bid >> 2, ks = bid & 3;       // 192 x 4
    int m0 = bm * 64;
    int s = m0 >> 12;
    const bf16* W = xproj_w + (size_t)s * 48 * NDI;
    int t = threadIdx.x;
    int w = t >> 6, l = t & 63;
    int quad = l >> 4, lan = l & 15;
    f32x4 acc[3];
    #pragma unroll
    for (int j = 0; j < 3; j++) acc[j] = (f32x4){0.f, 0.f, 0.f, 0.f};
    for (int kc0 = ks * 128; kc0 < ks * 128 + 128; kc0 += 64) {
        __syncthreads();
        #pragma unroll
        for (int i = 0; i < 2; i++) {          // A: 64x64 = 512 uint4
            int li = i * 256 + t;
            int row = li >> 3, col = (li & 7) * 8;
            *(uint4*)&As[row * 72 + col] =
                *(const uint4*)(xa + (size_t)(m0 + row) * NDI + kc0 + col);
        }
        {
            int li = t;                        // B: 48x64 = 384 uint4
            if (li < 384) {
                int row = li >> 3, col = (li & 7) * 8;
                *(uint4*)&Bs[row * 72 + col] =
                    *(const uint4*)(W + (size_t)row * NDI + kc0 + col);
            }
            int li2 = 256 + t;
            if (li2 < 384) {
                int row = li2 >> 3, col = (li2 & 7) * 8;
                *(uint4*)&Bs[row * 72 + col] =
                    *(const uint4*)(W + (size_t)row * NDI + kc0 + col);
            }
        }
        __syncthreads();
        #pragma unroll
        for (int kc = 0; kc < 64; kc += 32) {
            bf16x8 af = *(const bf16x8*)&As[(w * 16 + lan) * 72 + kc + quad * 8];
            #pragma unroll
            for (int j = 0; j < 3; j++) {
                bf16x8 bf = *(const bf16x8*)&Bs[(j * 16 + lan) * 72 + kc + quad * 8];
                acc[j] = __builtin_amdgcn_mfma_f32_16x16x32_bf16(af, bf, acc[j], 0, 0, 0);
            }
        }
    }
    float* dst = xpart + (size_t)ks * (12288 * 48);
    #pragma unroll
    for (int j = 0; j < 3; j++) {
        int e = j * 16 + lan;
        #pragma unroll
        for (int r = 0; r < 4; r++) {
            int m = m0 + w * 16 + quad * 4 + r;
            dst[(size_t)m * 48 + e] = acc[j][r];
        }
    }
}

// ---------------- K4b: reduce split-K + dt GEMM (K=16) + softplus ----------------
__global__ __launch_bounds__(256) void k_dt2(
    const float* __restrict__ xpart, const bf16* __restrict__ dt_w,
    const bf16* __restrict__ dt_b, float* __restrict__ xdbl, bf16* __restrict__ dt)
{
    __shared__ float xs[4][48];
    int row0 = blockIdx.x * 4;
    int s = row0 >> 12;
    int t = threadIdx.x;
    if (t < 192) {
        int r = t / 48, e = t % 48;
        size_t base = (size_t)(row0 + r) * 48 + e;
        const size_t seg = (size_t)12288 * 48;
        float v = xpart[base] + xpart[base + seg] + xpart[base + 2 * seg] + xpart[base + 3 * seg];
        xs[r][e] = v;
        if (e >= 16) xdbl[base] = v;    // B and C columns for the scans
    }
    __syncthreads();
    #pragma unroll
    for (int dd = 0; dd < 2; dd++) {
        int d = t + dd * 256;
        const uint4* wp = (const uint4*)(dt_w + ((size_t)s * NDI + d) * NDTR);
        float w[16]; dec8(wp[0], w); dec8(wp[1], w + 8);
        float bias = b2f(dt_b[s * NDI + d]);
        #pragma unroll
        for (int r = 0; r < 4; r++) {
            float a = bias;
            #pragma unroll
            for (int j = 0; j < 16; j++) a += w[j] * xs[r][j];
            a = (a > 20.0f) ? a : log1pf(__expf(a));   // softplus
            dt[(size_t)(row0 + r) * NDI + d] = __float2bfloat16(a);
        }
    }
}

// ---------------- K5a: chunk-local scan (LDS-staged) -> Hend, Pprod ----------------
__global__ __launch_bounds__(256) void k_scan1(
    const bf16* __restrict__ dt, const bf16* __restrict__ xa,
    const bf16* __restrict__ A_log, const float* __restrict__ xdbl,
    float* __restrict__ Hend, float* __restrict__ Pprod)
{
    __shared__ bf16 dts[LCH * 256];
    __shared__ bf16 xas[LCH * 256];
    __shared__ float Bs[LCH * NS];
    int bid = blockIdx.x;                 // 6 * NCH * 2 = 768
    int sb = bid / (NCH * 2);
    int rem = bid % (NCH * 2);
    int chunk = rem >> 1, dg = rem & 1;
    int s = sb >> 1;
    int t = threadIdx.x;
    int d = dg * 256 + t;
    int n0 = chunk * LCH;
    size_t rowbase = (size_t)sb * NN;
    const bf16* dtg = dt + (rowbase + n0) * NDI + dg * 256;
    const bf16* xag = xa + (rowbase + n0) * NDI + dg * 256;
    #pragma unroll
    for (int i = 0; i < 4; i++) {
        int li = i * 256 + t;
        int row = li >> 5, q = li & 31;
        ((uint4*)dts)[li] = *(const uint4*)(dtg + (size_t)row * NDI + q * 8);
        ((uint4*)xas)[li] = *(const uint4*)(xag + (size_t)row * NDI + q * 8);
    }
    if (t < 128) {
        int row = t >> 2, q = t & 3;
        ((float4*)Bs)[t] = ((const float4*)(xdbl + (rowbase + n0 + row) * 48 + 16))[q];
    }
    float A[16];
    {
        const uint4* ap = (const uint4*)(A_log + ((size_t)s * NDI + d) * NS);
        float al[8]; dec8(ap[0], al);
        #pragma unroll
        for (int i = 0; i < 8; i++) A[i] = -__expf(al[i]);
        dec8(ap[1], al);
        #pragma unroll
        for (int i = 0; i < 8; i++) A[8 + i] = -__expf(al[i]);
    }
    __syncthreads();
    float h[16], P[16];
    #pragma unroll
    for (int i = 0; i < 16; i++) { h[i] = 0.0f; P[i] = 1.0f; }
    #pragma unroll 4
    for (int nl = 0; nl < LCH; nl++) {
        float dtv = b2f(dts[nl * 256 + t]);
        float xav = b2f(xas[nl * 256 + t]);
        float bcom = dtv * xav;
        const float4* br = (const float4*)&Bs[nl * NS];
        float4 b0 = br[0], b1 = br[1], b2 = br[2], b3 = br[3];
        float bv[16] = {b0.x,b0.y,b0.z,b0.w,b1.x,b1.y,b1.z,b1.w,
                        b2.x,b2.y,b2.z,b2.w,b3.x,b3.y,b3.z,b3.w};
        #pragma unroll
        for (int st = 0; st < 16; st++) {
            float dA = __expf(dtv * A[st]);
            h[st] = dA * h[st] + bcom * bv[st];
            P[st] *= dA;
        }
    }
    size_t base = ((size_t)(chunk * 6 + sb) * NS) * NDI + d;
    #pragma unroll
    for (int st = 0; st < 16; st++) {
        Hend[base + (size_t)st * NDI] = h[st];
        Pprod[base + (size_t)st * NDI] = P[st];
    }
}

// ---------------- K5b: prefix over chunk summaries, parallel over states ----------------
__global__ __launch_bounds__(256) void k_scomb(float* __restrict__ Hend, const float* __restrict__ Pprod)
{
    int idx = blockIdx.x * 256 + threadIdx.x;   // 49152 = 6 sb * 16 st * 512 d
    int sb = idx >> 13;
    int rem = idx & 8191;
    int st = rem >> 9, d = rem & 511;
    float h = 0.0f;
    const size_t stride = (size_t)6 * NS * NDI;
    size_t g = ((size_t)sb * NS + st) * NDI + d;
    #pragma unroll 4
    for (int c = 0; c < NCH; c++) {
        float He = Hend[g], Pp = Pprod[g];
        Hend[g] = h;                 // h_start for this chunk
        h = He + Pp * h;
        g += stride;
    }
}

// ---------------- K5c: re-scan chunks from h_start (LDS-staged), C-dot + gating -> y ----------------
__global__ __launch_bounds__(256) void k_scan2(
    const bf16* __restrict__ dt, const bf16* __restrict__ xa, const bf16* __restrict__ z,
    const float* __restrict__ xdbl,
    const bf16* __restrict__ A_log, const bf16* __restrict__ Dp,
    const float* __restrict__ Hstart, bf16* __restrict__ y)
{
    __shared__ bf16 dts[LCH * 256];
    __shared__ bf16 xas[LCH * 256];
    __shared__ bf16 zs[LCH * 256];
    __shared__ float Bs[LCH * NS], Cs[LCH * NS];
    int bid = blockIdx.x;
    int sb = bid / (NCH * 2);
    int rem = bid % (NCH * 2);
    int chunk = rem >> 1, dg = rem & 1;
    int s = sb >> 1;
    int t = threadIdx.x;
    int d = dg * 256 + t;
    int n0 = chunk * LCH;
    size_t rowbase = (size_t)sb * NN;
    const bf16* dtg = dt + (rowbase + n0) * NDI + dg * 256;
    const bf16* xag = xa + (rowbase + n0) * NDI + dg * 256;
    const bf16* zg  = z  + (rowbase + n0) * NDI + dg * 256;
    #pragma unroll
    for (int i = 0; i < 4; i++) {
        int li = i * 256 + t;
        int row = li >> 5, q = li & 31;
        ((uint4*)dts)[li] = *(const uint4*)(dtg + (size_t)row * NDI + q * 8);
        ((uint4*)xas)[li] = *(const uint4*)(xag + (size_t)row * NDI + q * 8);
        ((uint4*)zs)[li]  = *(const uint4*)(zg  + (size_t)row * NDI + q * 8);
    }
    if (t < 128) {
        int row = t >> 2, q = t & 3;
        ((float4*)Bs)[t] = ((const float4*)(xdbl + (rowbase + n0 + row) * 48 + 16))[q];
    } else {
        int t2 = t - 128;
        int row = t2 >> 2, q = t2 & 3;
        ((float4*)Cs)[t2] = ((const float4*)(xdbl + (rowbase + n0 + row) * 48 + 32))[q];
    }
    float A[16];
    {
        const uint4* ap = (const uint4*)(A_log + ((size_t)s * NDI + d) * NS);
        float al[8]; dec8(ap[0], al);
        #pragma unroll
        for (int i = 0; i < 8; i++) A[i] = -__expf(al[i]);
        dec8(ap[1], al);
        #pragma unroll
        for (int i = 0; i < 8; i++) A[8 + i] = -__expf(al[i]);
    }
    float Dpv = b2f(Dp[s * NDI + d]);
    float h[16];
    {
        size_t base = ((size_t)(chunk * 6 + sb) * NS) * NDI + d;
        #pragma unroll
        for (int st = 0; st < 16; st++) h[st] = Hstart[base + (size_t)st * NDI];
    }
    __syncthreads();
    bf16* yp = y + (rowbase + n0) * NDI + d;
    #pragma unroll 4
    for (int nl = 0; nl < LCH; nl++) {
        float dtv = b2f(dts[nl * 256 + t]);
        float xav = b2f(xas[nl * 256 + t]);
        float zz  = b2f(zs[nl * 256 + t]);
        float bcom = dtv * xav;
        const float4* br = (const float4*)&Bs[nl * NS];
        const float4* cr = (const float4*)&Cs[nl * NS];
        float4 b0 = br[0], b1 = br[1], b2 = br[2], b3 = br[3];
        float4 c0 = cr[0], c1 = cr[1], c2 = cr[2], c3 = cr[3];
        float bv[16] = {b0.x,b0.y,b0.z,b0.w,b1.x,b1.y,b1.z,b1.w,
                        b2.x,b2.y,b2.z,b2.w,b3.x,b3.y,b3.z,b3.w};
        float cv[16] = {c0.x,c0.y,c0.z,c0.w,c1.x,c1.y,c1.z,c1.w,
                        c2.x,c2.y,c2.z,c2.w,c3.x,c3.y,c3.z,c3.w};
        float yacc = 0.0f;
        #pragma unroll
        for (int st = 0; st < 16; st++) {
            float dA = __expf(dtv * A[st]);
            h[st] = dA * h[st] + bcom * bv[st];
            yacc += h[st] * cv[st];
        }
        float yv = yacc + xav * Dpv;
        yv *= zz / (1.0f + __expf(-zz));
        yp[(size_t)nl * NDI] = __float2bfloat16(yv);
    }
}

// ---------------- K6: out_proj tiled MFMA + residual -> proc, fused pooling ----------------
__global__ __launch_bounds__(256) void k_outproj_t(
    const bf16* __restrict__ y, const bf16* __restrict__ out_w,
    const bf16* __restrict__ e_, const bf16* __restrict__ bl, const bf16* __restrict__ sp,
    bf16* __restrict__ proc, float* __restrict__ pooled)
{
    __shared__ bf16 As[128 * 72];
    __shared__ bf16 Bs[64 * 72];
    __shared__ float colsum[64];
    int bid = blockIdx.x;
    int bm = bid >> 2, bn = bid & 3;
    int m0 = bm * 128, e0 = bn * 64;
    int s = m0 >> 12;
    const bf16* W = out_w + (size_t)s * ND * NDI;
    int t = threadIdx.x;
    int w = t >> 6, l = t & 63;
    int quad = l >> 4, lan = l & 15;
    f32x4 acc[2][4];
    #pragma unroll
    for (int mi = 0; mi < 2; mi++)
        #pragma unroll
        for (int j = 0; j < 4; j++) acc[mi][j] = (f32x4){0.f, 0.f, 0.f, 0.f};
    for (int kc0 = 0; kc0 < 512; kc0 += 64) {
        __syncthreads();
        #pragma unroll
        for (int i = 0; i < 4; i++) {
            int li = i * 256 + t;
            int row = li >> 3, col = (li & 7) * 8;
            *(uint4*)&As[row * 72 + col] =
                *(const uint4*)(y + (size_t)(m0 + row) * NDI + kc0 + col);
        }
        #pragma unroll
        for (int i = 0; i < 2; i++) {
            int li = i * 256 + t;
            int row = li >> 3, col = (li & 7) * 8;
            *(uint4*)&Bs[row * 72 + col] =
                *(const uint4*)(W + (size_t)(e0 + row) * NDI + kc0 + col);
        }
        __syncthreads();
        #pragma unroll
        for (int kc = 0; kc < 64; kc += 32) {
            bf16x8 af[2], bf[4];
            #pragma unroll
            for (int mi = 0; mi < 2; mi++)
                af[mi] = *(const bf16x8*)&As[(w * 32 + mi * 16 + lan) * 72 + kc + quad * 8];
            #pragma unroll
            for (int j = 0; j < 4; j++)
                bf[j] = *(const bf16x8*)&Bs[(j * 16 + lan) * 72 + kc + quad * 8];
            #pragma unroll
            for (int mi = 0; mi < 2; mi++)
                #pragma unroll
                for (int j = 0; j < 4; j++)
                    acc[mi][j] = __builtin_amdgcn_mfma_f32_16x16x32_bf16(af[mi], bf[j], acc[mi][j], 0, 0, 0);
        }
    }
    if (t < 64) colsum[t] = 0.0f;
    __syncthreads();
    const bf16* xin = (s == 0) ? e_ : ((s == 1) ? bl : sp);
    int b = (m0 >> 11) & 1;
    #pragma unroll
    for (int mi = 0; mi < 2; mi++) {
        #pragma unroll
        for (int j = 0; j < 4; j++) {
            int e = e0 + j * 16 + lan;
            float ps = 0.0f;
            #pragma unroll
            for (int r = 0; r < 4; r++) {
                int m = m0 + w * 32 + mi * 16 + quad * 4 + r;
                int n = m & (NN - 1);
                float v = acc[mi][j][r] + b2f(xin[((size_t)(b * NN + n)) * ND + e]);
                proc[(size_t)m * ND + e] = __float2bfloat16(v);
                ps += v;
            }
            atomicAdd(&colsum[j * 16 + lan], ps);
        }
    }
    __syncthreads();
    if (t < 64) atomicAdd(&pooled[b * 768 + s * 256 + e0 + t], colsum[t]);
}

// ---------------- K9: final proj tiled MFMA + fused coeffs + weighted residual -> d_out ----------------
__global__ __launch_bounds__(256) void k_final_t(
    const bf16* __restrict__ proc, const bf16* __restrict__ proj_w,
    const bf16* __restrict__ proj_b, const float* __restrict__ pooled,
    const bf16* __restrict__ agg_w1, const bf16* __restrict__ agg_b1,
    const bf16* __restrict__ agg_w2, const bf16* __restrict__ agg_b2,
    const bf16* __restrict__ temp,
    const int* __restrict__ flag, void* __restrict__ out)
{
    __shared__ bf16 As[128 * 72];
    __shared__ bf16 Bs[64 * 72];
    __shared__ float hb[256];
    __shared__ float lg[3];
    __shared__ float cf[3];
    int bid = blockIdx.x;
    int bm = bid >> 2, bn = bid & 3;
    int m0 = bm * 128, e0 = bn * 64;
    int b = m0 >> 11;                 // batch, const per block
    int nbase = m0 & (NN - 1);
    int t = threadIdx.x;
    int w = t >> 6, l = t & 63;
    int quad = l >> 4, lan = l & 15;
    // ---- per-block redundant coeff computation (gelu MLP + double softmax) ----
    {
        float dot = 0.0f;
        const uint4* wp = (const uint4*)(agg_w1 + (size_t)t * 768);
        for (int k8 = 0; k8 < 96; k8++) {
            float wv[8]; dec8(wp[k8], wv);
            const float* pp = pooled + b * 768 + k8 * 8;
            #pragma unroll
            for (int j = 0; j < 8; j++) dot += wv[j] * pp[j];
        }
        float x = b2f(agg_b1[t]) + dot * (1.0f / NN);
        float inner = 0.7978845608028654f * (x + 0.044715f * x * x * x);
        hb[t] = 0.5f * x * (1.0f + tanhf(inner));
        __syncthreads();
        if (t < 3) {
            float ll = b2f(agg_b2[t]);
            const bf16* w2 = agg_w2 + t * 256;
            for (int d2 = 0; d2 < 256; d2++) ll += b2f(w2[d2]) * hb[d2];
            lg[t] = ll;
        }
        __syncthreads();
        if (t == 0) {
            float m = fmaxf(lg[0], fmaxf(lg[1], lg[2]));
            float e0f = __expf(lg[0] - m), e1 = __expf(lg[1] - m), e2 = __expf(lg[2] - m);
            float iS = 1.0f / (e0f + e1 + e2);
            float c0 = e0f * iS, c1 = e1 * iS, c2 = e2 * iS;
            float tt = b2f(temp[0]) + 1e-6f;
            float m2 = fmaxf(c0, fmaxf(c1, c2)) / tt;
            e0f = __expf(c0 / tt - m2); e1 = __expf(c1 / tt - m2); e2 = __expf(c2 / tt - m2);
            iS = 1.0f / (e0f + e1 + e2);
            cf[0] = e0f * iS; cf[1] = e1 * iS; cf[2] = e2 * iS;
        }
    }
    f32x4 acc[2][4];
    #pragma unroll
    for (int mi = 0; mi < 2; mi++)
        #pragma unroll
        for (int j = 0; j < 4; j++) acc[mi][j] = (f32x4){0.f, 0.f, 0.f, 0.f};
    for (int kc0 = 0; kc0 < 768; kc0 += 64) {
        int sA = kc0 >> 8, kd0 = kc0 & 255;
        const bf16* Asrc = proc + ((size_t)(sA * NB + b) * NN + nbase) * ND + kd0;
        __syncthreads();
        #pragma unroll
        for (int i = 0; i < 4; i++) {
            int li = i * 256 + t;
            int row = li >> 3, col = (li & 7) * 8;
            *(uint4*)&As[row * 72 + col] = *(const uint4*)(Asrc + (size_t)row * ND + col);
        }
        #pragma unroll
        for (int i = 0; i < 2; i++) {
            int li = i * 256 + t;
            int row = li >> 3, col = (li & 7) * 8;
            *(uint4*)&Bs[row * 72 + col] =
                *(const uint4*)(proj_w + (size_t)(e0 + row) * 768 + kc0 + col);
        }
        __syncthreads();
        #pragma unroll
        for (int kc = 0; kc < 64; kc += 32) {
            bf16x8 af[2], bf[4];
            #pragma unroll
            for (int mi = 0; mi < 2; mi++)
                af[mi] = *(const bf16x8*)&As[(w * 32 + mi * 16 + lan) * 72 + kc + quad * 8];
            #pragma unroll
            for (int j = 0; j < 4; j++)
                bf[j] = *(const bf16x8*)&Bs[(j * 16 + lan) * 72 + kc + quad * 8];
            #pragma unroll
            for (int mi = 0; mi < 2; mi++)
                #pragma unroll
                for (int j = 0; j < 4; j++)
                    acc[mi][j] = __builtin_amdgcn_mfma_f32_16x16x32_bf16(af[mi], bf[j], acc[mi][j], 0, 0, 0);
        }
    }
    float c0 = cf[0], c1 = cf[1], c2 = cf[2];
    int f = flag[0];
    #pragma unroll
    for (int mi = 0; mi < 2; mi++) {
        #pragma unroll
        for (int j = 0; j < 4; j++) {
            int e = e0 + j * 16 + lan;
            float pb = b2f(proj_b[e]);
            #pragma unroll
            for (int r = 0; r < 4; r++) {
                int m = m0 + w * 32 + mi * 16 + quad * 4 + r;
                int n = m & (NN - 1);
                size_t pbase = ((size_t)b * NN + n) * ND + e;
                float wres = c0 * b2f(proc[pbase])
                           + c1 * b2f(proc[pbase + (size_t)1 * NB * NN * ND])
                           + c2 * b2f(proc[pbase + (size_t)2 * NB * NN * ND]);
                float v = acc[mi][j][r] + pb + wres;
                if (f) ((float*)out)[(size_t)m * ND + e] = v;
                else   ((bf16*)out)[(size_t)m * ND + e] = __float2bfloat16(v);
            }
        }
    }
}

extern "C" void kernel_launch(void* const* d_in, const int* in_sizes, int n_in,
                              void* d_out, int out_size, void* d_ws, size_t ws_size,
                              hipStream_t stream)
{
    // ---- workspace layout (bytes), total ~103.3 MB (ws is ~256 MB) ----
    char* w8 = (char*)d_ws;
    int*   flagp   = (int*)(w8);
    bf16*  cvt     = (bf16*)(w8 + 16);              // 9,710,144 B
    bf16*  xn      = (bf16*)(w8 + 9710160);         // 6,291,456 B (xn -> proc)
    bf16*  xcb     = (bf16*)(w8 + 16001616);        // 12,582,912 B (xc, then y)
    bf16*  zb      = (bf16*)(w8 + 28584528);
    bf16*  xab     = (bf16*)(w8 + 41167440);
    bf16*  dtb     = (bf16*)(w8 + 53750352);
    float* xdblb   = (float*)(w8 + 66333264);       // 2,359,296 B
    float* pooledb = (float*)(w8 + 68692560);       // 6,144 B
    float* Hendb   = (float*)(w8 + 68698736);       // 12,582,912 B
    float* Pprodb  = (float*)(w8 + 81281648);       // 12,582,912 B
    float* xpartb  = (float*)(w8 + 93864560);       // 9,437,184 B -> end 103,301,744
    bf16*  procb   = xn;                            // proc after scan2 completes

    const bf16* c_edge   = cvt + 0;
    const bf16* c_blob   = cvt + 1048576;
    const bf16* c_spec   = cvt + 2097152;
    const bf16* c_inw    = cvt + 3145728;
    const bf16* c_outw   = cvt + 3932160;
    const bf16* c_xpw    = cvt + 4325376;
    const bf16* c_dtw    = cvt + 4399104;
    const bf16* c_alog   = cvt + 4423680;
    const bf16* c_agg1   = cvt + 4448256;
    const bf16* c_prjw   = cvt + 4644864;
    const bf16* c_convw  = cvt + 4841472;
    const bf16* c_convb  = cvt + 4849152;
    const bf16* c_dtb    = cvt + 4850688;
    const bf16* c_dp     = cvt + 4852224;
    const bf16* c_agb1   = cvt + 4853760;
    const bf16* c_agw2   = cvt + 4854016;
    const bf16* c_agb2   = cvt + 4854784;
    const bf16* c_prjb   = cvt + 4854800;
    const bf16* c_temp   = cvt + 4855056;

    CvtArgs ca;
    for (int i = 0; i < 21; i++) ca.s[i] = d_in[i];
    // merged LN + convert: 12288 LN blocks + 6678 weight-convert blocks
    k_ln_cvt<<<12288 + (1709316 + 255) / 256, 256, 0, stream>>>(ca, flagp, cvt, pooledb, xn);
    k_inproj_t<<<96 * 8, 256, 0, stream>>>(xn, c_inw, xcb, zb);
    k_conv<<<6 * NN * NDI / 8 / 256, 256, 0, stream>>>(xcb, c_convw, c_convb, xab);
    k_xproj_t<<<192 * 4, 256, 0, stream>>>(xab, c_xpw, xpartb);
    k_dt2<<<3072, 256, 0, stream>>>(xpartb, c_dtw, c_dtb, xdblb, dtb);
    k_scan1<<<6 * NCH * 2, 256, 0, stream>>>(dtb, xab, c_alog, xdblb, Hendb, Pprodb);
    k_scomb<<<192, 256, 0, stream>>>(Hendb, Pprodb);
    k_scan2<<<6 * NCH * 2, 256, 0, stream>>>(dtb, xab, zb, xdblb, c_alog, c_dp, Hendb, xcb);
    k_outproj_t<<<96 * 4, 256, 0, stream>>>(xcb, c_outw, c_edge, c_blob, c_spec, procb, pooledb);
    k_final_t<<<32 * 4, 256, 0, stream>>>(procb, c_prjw, c_prjb, pooledb,
                                          c_agg1, c_agb1, c_agw2, c_agb2, c_temp,
                                          flagp, d_out);
}

// Round 15
// 312.883 us; speedup vs baseline: 1.2057x; 1.0313x over previous
//
#include <hip/hip_runtime.h>
#include <hip/hip_bf16.h>

#define NB 2
#define NN 2048
#define ND 256
#define NS 16
#define NDC 4
#define NDI 512
#define NDTR 16
#define LCH 32    // chunk length for parallel scan
#define NCH 64    // number of chunks (LCH*NCH == NN)

typedef __hip_bfloat16 bf16;
typedef __attribute__((ext_vector_type(8))) __bf16 bf16x8;
typedef __attribute__((ext_vector_type(4))) float f32x4;

__device__ __forceinline__ float b2f(bf16 h) { return __bfloat162float(h); }

__device__ __forceinline__ void dec8(const uint4 u, float w[8]) {
    union { unsigned u; float f; } c;
    c.u = u.x << 16;          w[0] = c.f;
    c.u = u.x & 0xffff0000u;  w[1] = c.f;
    c.u = u.y << 16;          w[2] = c.f;
    c.u = u.y & 0xffff0000u;  w[3] = c.f;
    c.u = u.z << 16;          w[4] = c.f;
    c.u = u.z & 0xffff0000u;  w[5] = c.f;
    c.u = u.w << 16;          w[6] = c.f;
    c.u = u.w & 0xffff0000u;  w[7] = c.f;
}

// ---------------- K0+K1 merged: LN+feature-convert (blocks < 12288) | weight convert (rest) ----------------
struct CvtArgs { const void* s[21]; };
__device__ __constant__ const int seg_cum[22] = {
    0, 1048576, 2097152, 3145728, 3146496, 3147264, 3933696, 3939840,
    3941376, 4015104, 4039680, 4041216, 4065792, 4067328, 4460544, 4460545,
    4657153, 4657409, 4658177, 4658180, 4854788, 4855044 };
__device__ __constant__ const int seg_dst[21] = {
    0,        1048576,  2097152,  4847616, 4848384, 3145728, 4841472, 4849152, 4325376,
    4399104,  4850688,  4423680,  4852224, 3932160, 4855056, 4448256, 4853760, 4854016,
    4854784,  4644864,  4854800 };

__global__ __launch_bounds__(256) void k_ln_cvt(
    CvtArgs a, int* __restrict__ flag,
    bf16* __restrict__ cvt, float* __restrict__ pooled, bf16* __restrict__ xn)
{
    int t = threadIdx.x;
    unsigned v0 = ((const unsigned*)a.s[3])[0];
    int f = ((v0 & 0xFFFFu) == 0u);
    if (blockIdx.x >= 12288) {
        // ---- weight conversion path ----
        int idx0 = (blockIdx.x - 12288) * 256 + t;
        if (idx0 == 0) flag[0] = f;
        if (idx0 < 1536) pooled[idx0] = 0.0f;
        int idx = idx0 + 3145728;
        if (idx >= 4855044) return;
        int seg = 3;
        #pragma unroll
        for (int i = 4; i < 21; i++) if (idx >= seg_cum[i]) seg = i;
        int off = idx - seg_cum[seg];
        bf16 v;
        if (f) v = __float2bfloat16(((const float*)a.s[seg])[off]);
        else   v = ((const bf16*)a.s[seg])[off];
        cvt[seg_dst[seg] + off] = v;
        return;
    }
    // ---- layernorm + feature conversion path ----
    int row = blockIdx.x;            // sb*NN + n, sb = s*NB + b
    int sb = row >> 11, n = row & (NN - 1);
    int s = sb >> 1, b = sb & 1;
    const void* xin = a.s[s];
    size_t gi = ((size_t)(b << 11) + n) * ND + t;
    float v = f ? ((const float*)xin)[gi] : b2f(((const bf16*)xin)[gi]);
    cvt[(size_t)s * 1048576 + gi] = __float2bfloat16(v);
    float s1 = v, s2 = v * v;
    #pragma unroll
    for (int m = 1; m < 64; m <<= 1) { s1 += __shfl_xor(s1, m); s2 += __shfl_xor(s2, m); }
    __shared__ float r1[4], r2[4];
    int w = t >> 6;
    if ((t & 63) == 0) { r1[w] = s1; r2[w] = s2; }
    __syncthreads();
    float mean = (r1[0] + r1[1] + r1[2] + r1[3]) * (1.0f / ND);
    float ms   = (r2[0] + r2[1] + r2[2] + r2[3]) * (1.0f / ND);
    float inv = rsqrtf(ms - mean * mean + 1e-5f);
    const void* nw_raw = a.s[3];
    const void* nb_raw = a.s[4];
    float wv = f ? ((const float*)nw_raw)[s * ND + t] : b2f(((const bf16*)nw_raw)[s * ND + t]);
    float bv = f ? ((const float*)nb_raw)[s * ND + t] : b2f(((const bf16*)nb_raw)[s * ND + t]);
    xn[(size_t)row * ND + t] = __float2bfloat16((v - mean) * inv * wv + bv);
}

// ---------------- K2: in_proj tiled MFMA GEMM 128x128 -> xc, z ----------------
__global__ __launch_bounds__(256) void k_inproj_t(
    const bf16* __restrict__ xn, const bf16* __restrict__ in_w,
    bf16* __restrict__ xc, bf16* __restrict__ z)
{
    __shared__ bf16 As[128 * 72];
    __shared__ bf16 Bs[128 * 72];
    int bid = blockIdx.x;
    int bm = bid >> 3, bn = bid & 7;           // 96 x 8
    int m0 = bm * 128, e0 = bn * 128;
    int s = m0 >> 12;
    const bf16* W = in_w + (size_t)s * (2 * NDI) * ND;
    int t = threadIdx.x;
    int w = t >> 6, l = t & 63;
    int wm = w >> 1, wn = w & 1;
    int quad = l >> 4, lan = l & 15;
    f32x4 acc[4][4];
    #pragma unroll
    for (int mi = 0; mi < 4; mi++)
        #pragma unroll
        for (int j = 0; j < 4; j++) acc[mi][j] = (f32x4){0.f, 0.f, 0.f, 0.f};
    for (int kc0 = 0; kc0 < 256; kc0 += 64) {
        __syncthreads();
        #pragma unroll
        for (int i = 0; i < 4; i++) {
            int li = i * 256 + t;
            int row = li >> 3, col = (li & 7) * 8;
            *(uint4*)&As[row * 72 + col] =
                *(const uint4*)(xn + (size_t)(m0 + row) * ND + kc0 + col);
        }
        #pragma unroll
        for (int i = 0; i < 4; i++) {
            int li = i * 256 + t;
            int row = li >> 3, col = (li & 7) * 8;
            *(uint4*)&Bs[row * 72 + col] =
                *(const uint4*)(W + (size_t)(e0 + row) * ND + kc0 + col);
        }
        __syncthreads();
        #pragma unroll
        for (int kc = 0; kc < 64; kc += 32) {
            bf16x8 af[4], bf[4];
            #pragma unroll
            for (int mi = 0; mi < 4; mi++)
                af[mi] = *(const bf16x8*)&As[(wm * 64 + mi * 16 + lan) * 72 + kc + quad * 8];
            #pragma unroll
            for (int j = 0; j < 4; j++)
                bf[j] = *(const bf16x8*)&Bs[(wn * 64 + j * 16 + lan) * 72 + kc + quad * 8];
            #pragma unroll
            for (int mi = 0; mi < 4; mi++)
                #pragma unroll
                for (int j = 0; j < 4; j++)
                    acc[mi][j] = __builtin_amdgcn_mfma_f32_16x16x32_bf16(af[mi], bf[j], acc[mi][j], 0, 0, 0);
        }
    }
    #pragma unroll
    for (int mi = 0; mi < 4; mi++) {
        #pragma unroll
        for (int j = 0; j < 4; j++) {
            int e = e0 + wn * 64 + j * 16 + lan;
            bf16* dst = (e < NDI) ? xc : z;
            int ec = e & (NDI - 1);
            #pragma unroll
            for (int r = 0; r < 4; r++) {
                int m = m0 + wm * 64 + mi * 16 + quad * 4 + r;
                dst[(size_t)m * NDI + ec] = __float2bfloat16(acc[mi][j][r]);
            }
        }
    }
}

// ---------------- K3: causal depthwise conv (DC=4) + silu -> xa, vectorized x8 ----------------
__global__ __launch_bounds__(256) void k_conv(
    const bf16* __restrict__ xc, const bf16* __restrict__ conv_w,
    const bf16* __restrict__ conv_b, bf16* __restrict__ xa)
{
    int idx = blockIdx.x * 256 + threadIdx.x;   // over 6*2048*512/8 = 786432
    int d8 = (idx & 63) * 8;
    int rn = idx >> 6;                          // sb*NN + n
    int n = rn & (NN - 1);
    int sb = rn >> 11;
    int s = sb >> 1;
    const uint4* cwp = (const uint4*)(conv_w + ((size_t)s * NDI + d8) * NDC);
    float cwf[32];
    dec8(cwp[0], cwf); dec8(cwp[1], cwf + 8); dec8(cwp[2], cwf + 16); dec8(cwp[3], cwf + 24);
    float bias[8];
    dec8(*(const uint4*)(conv_b + (size_t)s * NDI + d8), bias);
    size_t g = (size_t)rn * NDI + d8;
    float xv[4][8];   // xv[tau] = x[n-tau]
    #pragma unroll
    for (int tau = 0; tau < 4; tau++) {
        if (n >= tau) dec8(*(const uint4*)(xc + g - (size_t)tau * NDI), xv[tau]);
        else
            #pragma unroll
            for (int j = 0; j < 8; j++) xv[tau][j] = 0.0f;
    }
    union { bf16 h[8]; uint4 u; } o;
    #pragma unroll
    for (int j = 0; j < 8; j++) {
        float a = bias[j];
        #pragma unroll
        for (int k = 0; k < 4; k++) a += cwf[j * 4 + k] * xv[3 - k][j];
        a = a / (1.0f + __expf(-a));
        o.h[j] = __float2bfloat16(a);
    }
    *(uint4*)(xa + g) = o.u;
}

// ---------------- K4a: x_proj MFMA, split-K x4 -> xpart[4][12288][48] fp32 ----------------
__global__ __launch_bounds__(256) void k_xproj_t(
    const bf16* __restrict__ xa, const bf16* __restrict__ xproj_w,
    float* __restrict__ xpart)
{
    __shared__ bf16 As[64 * 72];
    __shared__ bf16 Bs[48 * 72];
    int bid = blockIdx.x;
    int bm = bid >> 2, ks = bid & 3;       // 192 x 4
    int m0 = bm * 64;
    int s = m0 >> 12;
    const bf16* W = xproj_w + (size_t)s * 48 * NDI;
    int t = threadIdx.x;
    int w = t >> 6, l = t & 63;
    int quad = l >> 4, lan = l & 15;
    f32x4 acc[3];
    #pragma unroll
    for (int j = 0; j < 3; j++) acc[j] = (f32x4){0.f, 0.f, 0.f, 0.f};
    for (int kc0 = ks * 128; kc0 < ks * 128 + 128; kc0 += 64) {
        __syncthreads();
        #pragma unroll
        for (int i = 0; i < 2; i++) {          // A: 64x64 = 512 uint4
            int li = i * 256 + t;
            int row = li >> 3, col = (li & 7) * 8;
            *(uint4*)&As[row * 72 + col] =
                *(const uint4*)(xa + (size_t)(m0 + row) * NDI + kc0 + col);
        }
        {
            int li = t;                        // B: 48x64 = 384 uint4
            if (li < 384) {
                int row = li >> 3, col = (li & 7) * 8;
                *(uint4*)&Bs[row * 72 + col] =
                    *(const uint4*)(W + (size_t)row * NDI + kc0 + col);
            }
            int li2 = 256 + t;
            if (li2 < 384) {
                int row = li2 >> 3, col = (li2 & 7) * 8;
                *(uint4*)&Bs[row * 72 + col] =
                    *(const uint4*)(W + (size_t)row * NDI + kc0 + col);
            }
        }
        __syncthreads();
        #pragma unroll
        for (int kc = 0; kc < 64; kc += 32) {
            bf16x8 af = *(const bf16x8*)&As[(w * 16 + lan) * 72 + kc + quad * 8];
            #pragma unroll
            for (int j = 0; j < 3; j++) {
                bf16x8 bf = *(const bf16x8*)&Bs[(j * 16 + lan) * 72 + kc + quad * 8];
                acc[j] = __builtin_amdgcn_mfma_f32_16x16x32_bf16(af, bf, acc[j], 0, 0, 0);
            }
        }
    }
    float* dst = xpart + (size_t)ks * (12288 * 48);
    #pragma unroll
    for (int j = 0; j < 3; j++) {
        int e = j * 16 + lan;
        #pragma unroll
        for (int r = 0; r < 4; r++) {
            int m = m0 + w * 16 + quad * 4 + r;
            dst[(size_t)m * 48 + e] = acc[j][r];
        }
    }
}

// ---------------- K4b: reduce split-K + dt GEMM (K=16) + softplus ----------------
__global__ __launch_bounds__(256) void k_dt2(
    const float* __restrict__ xpart, const bf16* __restrict__ dt_w,
    const bf16* __restrict__ dt_b, float* __restrict__ xdbl, bf16* __restrict__ dt)
{
    __shared__ float xs[4][48];
    int row0 = blockIdx.x * 4;
    int s = row0 >> 12;
    int t = threadIdx.x;
    if (t < 192) {
        int r = t / 48, e = t % 48;
        size_t base = (size_t)(row0 + r) * 48 + e;
        const size_t seg = (size_t)12288 * 48;
        float v = xpart[base] + xpart[base + seg] + xpart[base + 2 * seg] + xpart[base + 3 * seg];
        xs[r][e] = v;
        if (e >= 16) xdbl[base] = v;    // B and C columns for the scans
    }
    __syncthreads();
    #pragma unroll
    for (int dd = 0; dd < 2; dd++) {
        int d = t + dd * 256;
        const uint4* wp = (const uint4*)(dt_w + ((size_t)s * NDI + d) * NDTR);
        float w[16]; dec8(wp[0], w); dec8(wp[1], w + 8);
        float bias = b2f(dt_b[s * NDI + d]);
        #pragma unroll
        for (int r = 0; r < 4; r++) {
            float a = bias;
            #pragma unroll
            for (int j = 0; j < 16; j++) a += w[j] * xs[r][j];
            a = (a > 20.0f) ? a : log1pf(__expf(a));   // softplus
            dt[(size_t)(row0 + r) * NDI + d] = __float2bfloat16(a);
        }
    }
}

// ---------------- K5a: chunk-local scan (LDS-staged) -> Hend, Pprod ----------------
__global__ __launch_bounds__(256) void k_scan1(
    const bf16* __restrict__ dt, const bf16* __restrict__ xa,
    const bf16* __restrict__ A_log, const float* __restrict__ xdbl,
    float* __restrict__ Hend, float* __restrict__ Pprod)
{
    __shared__ bf16 dts[LCH * 256];
    __shared__ bf16 xas[LCH * 256];
    __shared__ float Bs[LCH * NS];
    int bid = blockIdx.x;                 // 6 * NCH * 2 = 768
    int sb = bid / (NCH * 2);
    int rem = bid % (NCH * 2);
    int chunk = rem >> 1, dg = rem & 1;
    int s = sb >> 1;
    int t = threadIdx.x;
    int d = dg * 256 + t;
    int n0 = chunk * LCH;
    size_t rowbase = (size_t)sb * NN;
    const bf16* dtg = dt + (rowbase + n0) * NDI + dg * 256;
    const bf16* xag = xa + (rowbase + n0) * NDI + dg * 256;
    #pragma unroll
    for (int i = 0; i < 4; i++) {
        int li = i * 256 + t;
        int row = li >> 5, q = li & 31;
        ((uint4*)dts)[li] = *(const uint4*)(dtg + (size_t)row * NDI + q * 8);
        ((uint4*)xas)[li] = *(const uint4*)(xag + (size_t)row * NDI + q * 8);
    }
    if (t < 128) {
        int row = t >> 2, q = t & 3;
        ((float4*)Bs)[t] = ((const float4*)(xdbl + (rowbase + n0 + row) * 48 + 16))[q];
    }
    float A[16];
    {
        const uint4* ap = (const uint4*)(A_log + ((size_t)s * NDI + d) * NS);
        float al[8]; dec8(ap[0], al);
        #pragma unroll
        for (int i = 0; i < 8; i++) A[i] = -__expf(al[i]);
        dec8(ap[1], al);
        #pragma unroll
        for (int i = 0; i < 8; i++) A[8 + i] = -__expf(al[i]);
    }
    __syncthreads();
    float h[16], P[16];
    #pragma unroll
    for (int i = 0; i < 16; i++) { h[i] = 0.0f; P[i] = 1.0f; }
    #pragma unroll 4
    for (int nl = 0; nl < LCH; nl++) {
        float dtv = b2f(dts[nl * 256 + t]);
        float xav = b2f(xas[nl * 256 + t]);
        float bcom = dtv * xav;
        const float4* br = (const float4*)&Bs[nl * NS];
        float4 b0 = br[0], b1 = br[1], b2 = br[2], b3 = br[3];
        float bv[16] = {b0.x,b0.y,b0.z,b0.w,b1.x,b1.y,b1.z,b1.w,
                        b2.x,b2.y,b2.z,b2.w,b3.x,b3.y,b3.z,b3.w};
        #pragma unroll
        for (int st = 0; st < 16; st++) {
            float dA = __expf(dtv * A[st]);
            h[st] = dA * h[st] + bcom * bv[st];
            P[st] *= dA;
        }
    }
    size_t base = ((size_t)(chunk * 6 + sb) * NS) * NDI + d;
    #pragma unroll
    for (int st = 0; st < 16; st++) {
        Hend[base + (size_t)st * NDI] = h[st];
        Pprod[base + (size_t)st * NDI] = P[st];
    }
}

// ---------------- K5b: prefix over chunk summaries, parallel over states ----------------
__global__ __launch_bounds__(256) void k_scomb(float* __restrict__ Hend, const float* __restrict__ Pprod)
{
    int idx = blockIdx.x * 256 + threadIdx.x;   // 49152 = 6 sb * 16 st * 512 d
    int sb = idx >> 13;
    int rem = idx & 8191;
    int st = rem >> 9, d = rem & 511;
    float h = 0.0f;
    const size_t stride = (size_t)6 * NS * NDI;
    size_t g = ((size_t)sb * NS + st) * NDI + d;
    #pragma unroll 4
    for (int c = 0; c < NCH; c++) {
        float He = Hend[g], Pp = Pprod[g];
        Hend[g] = h;                 // h_start for this chunk
        h = He + Pp * h;
        g += stride;
    }
}

// ---------------- K5c: re-scan chunks from h_start (LDS-staged), C-dot + gating -> y ----------------
__global__ __launch_bounds__(256) void k_scan2(
    const bf16* __restrict__ dt, const bf16* __restrict__ xa, const bf16* __restrict__ z,
    const float* __restrict__ xdbl,
    const bf16* __restrict__ A_log, const bf16* __restrict__ Dp,
    const float* __restrict__ Hstart, bf16* __restrict__ y)
{
    __shared__ bf16 dts[LCH * 256];
    __shared__ bf16 xas[LCH * 256];
    __shared__ bf16 zs[LCH * 256];
    __shared__ float Bs[LCH * NS], Cs[LCH * NS];
    int bid = blockIdx.x;
    int sb = bid / (NCH * 2);
    int rem = bid % (NCH * 2);
    int chunk = rem >> 1, dg = rem & 1;
    int s = sb >> 1;
    int t = threadIdx.x;
    int d = dg * 256 + t;
    int n0 = chunk * LCH;
    size_t rowbase = (size_t)sb * NN;
    const bf16* dtg = dt + (rowbase + n0) * NDI + dg * 256;
    const bf16* xag = xa + (rowbase + n0) * NDI + dg * 256;
    const bf16* zg  = z  + (rowbase + n0) * NDI + dg * 256;
    #pragma unroll
    for (int i = 0; i < 4; i++) {
        int li = i * 256 + t;
        int row = li >> 5, q = li & 31;
        ((uint4*)dts)[li] = *(const uint4*)(dtg + (size_t)row * NDI + q * 8);
        ((uint4*)xas)[li] = *(const uint4*)(xag + (size_t)row * NDI + q * 8);
        ((uint4*)zs)[li]  = *(const uint4*)(zg  + (size_t)row * NDI + q * 8);
    }
    if (t < 128) {
        int row = t >> 2, q = t & 3;
        ((float4*)Bs)[t] = ((const float4*)(xdbl + (rowbase + n0 + row) * 48 + 16))[q];
    } else {
        int t2 = t - 128;
        int row = t2 >> 2, q = t2 & 3;
        ((float4*)Cs)[t2] = ((const float4*)(xdbl + (rowbase + n0 + row) * 48 + 32))[q];
    }
    float A[16];
    {
        const uint4* ap = (const uint4*)(A_log + ((size_t)s * NDI + d) * NS);
        float al[8]; dec8(ap[0], al);
        #pragma unroll
        for (int i = 0; i < 8; i++) A[i] = -__expf(al[i]);
        dec8(ap[1], al);
        #pragma unroll
        for (int i = 0; i < 8; i++) A[8 + i] = -__expf(al[i]);
    }
    float Dpv = b2f(Dp[s * NDI + d]);
    float h[16];
    {
        size_t base = ((size_t)(chunk * 6 + sb) * NS) * NDI + d;
        #pragma unroll
        for (int st = 0; st < 16; st++) h[st] = Hstart[base + (size_t)st * NDI];
    }
    __syncthreads();
    bf16* yp = y + (rowbase + n0) * NDI + d;
    #pragma unroll 4
    for (int nl = 0; nl < LCH; nl++) {
        float dtv = b2f(dts[nl * 256 + t]);
        float xav = b2f(xas[nl * 256 + t]);
        float zz  = b2f(zs[nl * 256 + t]);
        float bcom = dtv * xav;
        const float4* br = (const float4*)&Bs[nl * NS];
        const float4* cr = (const float4*)&Cs[nl * NS];
        float4 b0 = br[0], b1 = br[1], b2 = br[2], b3 = br[3];
        float4 c0 = cr[0], c1 = cr[1], c2 = cr[2], c3 = cr[3];
        float bv[16] = {b0.x,b0.y,b0.z,b0.w,b1.x,b1.y,b1.z,b1.w,
                        b2.x,b2.y,b2.z,b2.w,b3.x,b3.y,b3.z,b3.w};
        float cv[16] = {c0.x,c0.y,c0.z,c0.w,c1.x,c1.y,c1.z,c1.w,
                        c2.x,c2.y,c2.z,c2.w,c3.x,c3.y,c3.z,c3.w};
        float yacc = 0.0f;
        #pragma unroll
        for (int st = 0; st < 16; st++) {
            float dA = __expf(dtv * A[st]);
            h[st] = dA * h[st] + bcom * bv[st];
            yacc += h[st] * cv[st];
        }
        float yv = yacc + xav * Dpv;
        yv *= zz / (1.0f + __expf(-zz));
        yp[(size_t)nl * NDI] = __float2bfloat16(yv);
    }
}

// ---------------- K6: out_proj tiled MFMA + residual -> proc, fused pooling ----------------
__global__ __launch_bounds__(256) void k_outproj_t(
    const bf16* __restrict__ y, const bf16* __restrict__ out_w,
    const bf16* __restrict__ e_, const bf16* __restrict__ bl, const bf16* __restrict__ sp,
    bf16* __restrict__ proc, float* __restrict__ pooled)
{
    __shared__ bf16 As[128 * 72];
    __shared__ bf16 Bs[64 * 72];
    __shared__ float colsum[64];
    int bid = blockIdx.x;
    int bm = bid >> 2, bn = bid & 3;
    int m0 = bm * 128, e0 = bn * 64;
    int s = m0 >> 12;
    const bf16* W = out_w + (size_t)s * ND * NDI;
    int t = threadIdx.x;
    int w = t >> 6, l = t & 63;
    int quad = l >> 4, lan = l & 15;
    f32x4 acc[2][4];
    #pragma unroll
    for (int mi = 0; mi < 2; mi++)
        #pragma unroll
        for (int j = 0; j < 4; j++) acc[mi][j] = (f32x4){0.f, 0.f, 0.f, 0.f};
    for (int kc0 = 0; kc0 < 512; kc0 += 64) {
        __syncthreads();
        #pragma unroll
        for (int i = 0; i < 4; i++) {
            int li = i * 256 + t;
            int row = li >> 3, col = (li & 7) * 8;
            *(uint4*)&As[row * 72 + col] =
                *(const uint4*)(y + (size_t)(m0 + row) * NDI + kc0 + col);
        }
        #pragma unroll
        for (int i = 0; i < 2; i++) {
            int li = i * 256 + t;
            int row = li >> 3, col = (li & 7) * 8;
            *(uint4*)&Bs[row * 72 + col] =
                *(const uint4*)(W + (size_t)(e0 + row) * NDI + kc0 + col);
        }
        __syncthreads();
        #pragma unroll
        for (int kc = 0; kc < 64; kc += 32) {
            bf16x8 af[2], bf[4];
            #pragma unroll
            for (int mi = 0; mi < 2; mi++)
                af[mi] = *(const bf16x8*)&As[(w * 32 + mi * 16 + lan) * 72 + kc + quad * 8];
            #pragma unroll
            for (int j = 0; j < 4; j++)
                bf[j] = *(const bf16x8*)&Bs[(j * 16 + lan) * 72 + kc + quad * 8];
            #pragma unroll
            for (int mi = 0; mi < 2; mi++)
                #pragma unroll
                for (int j = 0; j < 4; j++)
                    acc[mi][j] = __builtin_amdgcn_mfma_f32_16x16x32_bf16(af[mi], bf[j], acc[mi][j], 0, 0, 0);
        }
    }
    if (t < 64) colsum[t] = 0.0f;
    __syncthreads();
    const bf16* xin = (s == 0) ? e_ : ((s == 1) ? bl : sp);
    int b = (m0 >> 11) & 1;
    #pragma unroll
    for (int mi = 0; mi < 2; mi++) {
        #pragma unroll
        for (int j = 0; j < 4; j++) {
            int e = e0 + j * 16 + lan;
            float ps = 0.0f;
            #pragma unroll
            for (int r = 0; r < 4; r++) {
                int m = m0 + w * 32 + mi * 16 + quad * 4 + r;
                int n = m & (NN - 1);
                float v = acc[mi][j][r] + b2f(xin[((size_t)(b * NN + n)) * ND + e]);
                proc[(size_t)m * ND + e] = __float2bfloat16(v);
                ps += v;
            }
            atomicAdd(&colsum[j * 16 + lan], ps);
        }
    }
    __syncthreads();
    if (t < 64) atomicAdd(&pooled[b * 768 + s * 256 + e0 + t], colsum[t]);
}

// ---------------- K9: final proj MFMA; coeff dot interleaved into K-loop ----------------
__global__ __launch_bounds__(256) void k_final_t(
    const bf16* __restrict__ proc, const bf16* __restrict__ proj_w,
    const bf16* __restrict__ proj_b, const float* __restrict__ pooled,
    const bf16* __restrict__ agg_w1, const bf16* __restrict__ agg_b1,
    const bf16* __restrict__ agg_w2, const bf16* __restrict__ agg_b2,
    const bf16* __restrict__ temp,
    const int* __restrict__ flag, void* __restrict__ out)
{
    __shared__ bf16 As[128 * 72];
    __shared__ bf16 Bs[64 * 72];
    __shared__ float hb[256];
    __shared__ float lg[3];
    __shared__ float cf[3];
    int bid = blockIdx.x;
    int bm = bid >> 2, bn = bid & 3;
    int m0 = bm * 128, e0 = bn * 64;
    int b = m0 >> 11;                 // batch, const per block
    int nbase = m0 & (NN - 1);
    int t = threadIdx.x;
    int w = t >> 6, l = t & 63;
    int quad = l >> 4, lan = l & 15;
    // coeff dot state (interleaved into K-loop below; VALU work hides under MFMA per m114)
    float dot = 0.0f;
    const uint4* awp = (const uint4*)(agg_w1 + (size_t)t * 768);
    const float* pp0 = pooled + b * 768;
    f32x4 acc[2][4];
    #pragma unroll
    for (int mi = 0; mi < 2; mi++)
        #pragma unroll
        for (int j = 0; j < 4; j++) acc[mi][j] = (f32x4){0.f, 0.f, 0.f, 0.f};
    for (int kc0 = 0; kc0 < 768; kc0 += 64) {
        int sA = kc0 >> 8, kd0 = kc0 & 255;
        const bf16* Asrc = proc + ((size_t)(sA * NB + b) * NN + nbase) * ND + kd0;
        __syncthreads();
        #pragma unroll
        for (int i = 0; i < 4; i++) {
            int li = i * 256 + t;
            int row = li >> 3, col = (li & 7) * 8;
            *(uint4*)&As[row * 72 + col] = *(const uint4*)(Asrc + (size_t)row * ND + col);
        }
        #pragma unroll
        for (int i = 0; i < 2; i++) {
            int li = i * 256 + t;
            int row = li >> 3, col = (li & 7) * 8;
            *(uint4*)&Bs[row * 72 + col] =
                *(const uint4*)(proj_w + (size_t)(e0 + row) * 768 + kc0 + col);
        }
        __syncthreads();
        #pragma unroll
        for (int kc = 0; kc < 64; kc += 32) {
            bf16x8 af[2], bf[4];
            #pragma unroll
            for (int mi = 0; mi < 2; mi++)
                af[mi] = *(const bf16x8*)&As[(w * 32 + mi * 16 + lan) * 72 + kc + quad * 8];
            #pragma unroll
            for (int j = 0; j < 4; j++)
                bf[j] = *(const bf16x8*)&Bs[(j * 16 + lan) * 72 + kc + quad * 8];
            #pragma unroll
            for (int mi = 0; mi < 2; mi++)
                #pragma unroll
                for (int j = 0; j < 4; j++)
                    acc[mi][j] = __builtin_amdgcn_mfma_f32_16x16x32_bf16(af[mi], bf[j], acc[mi][j], 0, 0, 0);
        }
        // interleaved coeff-dot chunk: 8 x uint4 of agg_w1 row per K-iteration
        {
            int k8base = (kc0 >> 6) * 8;
            #pragma unroll
            for (int k8 = k8base; k8 < k8base + 8; k8++) {
                float wv[8]; dec8(awp[k8], wv);
                const float* pp = pp0 + k8 * 8;
                #pragma unroll
                for (int j = 0; j < 8; j++) dot += wv[j] * pp[j];
            }
        }
    }
    // ---- finish coeffs (cheap): gelu -> 3-dot -> double softmax ----
    {
        float x = b2f(agg_b1[t]) + dot * (1.0f / NN);
        float inner = 0.7978845608028654f * (x + 0.044715f * x * x * x);
        hb[t] = 0.5f * x * (1.0f + tanhf(inner));
        __syncthreads();
        if (t < 3) {
            float ll = b2f(agg_b2[t]);
            const bf16* w2 = agg_w2 + t * 256;
            for (int d2 = 0; d2 < 256; d2++) ll += b2f(w2[d2]) * hb[d2];
            lg[t] = ll;
        }
        __syncthreads();
        if (t == 0) {
            float m = fmaxf(lg[0], fmaxf(lg[1], lg[2]));
            float e0f = __expf(lg[0] - m), e1 = __expf(lg[1] - m), e2 = __expf(lg[2] - m);
            float iS = 1.0f / (e0f + e1 + e2);
            float c0 = e0f * iS, c1 = e1 * iS, c2 = e2 * iS;
            float tt = b2f(temp[0]) + 1e-6f;
            float m2 = fmaxf(c0, fmaxf(c1, c2)) / tt;
            e0f = __expf(c0 / tt - m2); e1 = __expf(c1 / tt - m2); e2 = __expf(c2 / tt - m2);
            iS = 1.0f / (e0f + e1 + e2);
            cf[0] = e0f * iS; cf[1] = e1 * iS; cf[2] = e2 * iS;
        }
        __syncthreads();
    }
    float c0 = cf[0], c1 = cf[1], c2 = cf[2];
    int f = flag[0];
    #pragma unroll
    for (int mi = 0; mi < 2; mi++) {
        #pragma unroll
        for (int j = 0; j < 4; j++) {
            int e = e0 + j * 16 + lan;
            float pb = b2f(proj_b[e]);
            #pragma unroll
            for (int r = 0; r < 4; r++) {
                int m = m0 + w * 32 + mi * 16 + quad * 4 + r;
                int n = m & (NN - 1);
                size_t pbase = ((size_t)b * NN + n) * ND + e;
                float wres = c0 * b2f(proc[pbase])
                           + c1 * b2f(proc[pbase + (size_t)1 * NB * NN * ND])
                           + c2 * b2f(proc[pbase + (size_t)2 * NB * NN * ND]);
                float v = acc[mi][j][r] + pb + wres;
                if (f) ((float*)out)[(size_t)m * ND + e] = v;
                else   ((bf16*)out)[(size_t)m * ND + e] = __float2bfloat16(v);
            }
        }
    }
}

extern "C" void kernel_launch(void* const* d_in, const int* in_sizes, int n_in,
                              void* d_out, int out_size, void* d_ws, size_t ws_size,
                              hipStream_t stream)
{
    // ---- workspace layout (bytes), total ~103.3 MB (ws is ~256 MB) ----
    char* w8 = (char*)d_ws;
    int*   flagp   = (int*)(w8);
    bf16*  cvt     = (bf16*)(w8 + 16);              // 9,710,144 B
    bf16*  xn      = (bf16*)(w8 + 9710160);         // 6,291,456 B (xn -> proc)
    bf16*  xcb     = (bf16*)(w8 + 16001616);        // 12,582,912 B (xc, then y)
    bf16*  zb      = (bf16*)(w8 + 28584528);
    bf16*  xab     = (bf16*)(w8 + 41167440);
    bf16*  dtb     = (bf16*)(w8 + 53750352);
    float* xdblb   = (float*)(w8 + 66333264);       // 2,359,296 B
    float* pooledb = (float*)(w8 + 68692560);       // 6,144 B
    float* Hendb   = (float*)(w8 + 68698736);       // 12,582,912 B
    float* Pprodb  = (float*)(w8 + 81281648);       // 12,582,912 B
    float* xpartb  = (float*)(w8 + 93864560);       // 9,437,184 B -> end 103,301,744
    bf16*  procb   = xn;                            // proc after scan2 completes

    const bf16* c_edge   = cvt + 0;
    const bf16* c_blob   = cvt + 1048576;
    const bf16* c_spec   = cvt + 2097152;
    const bf16* c_inw    = cvt + 3145728;
    const bf16* c_outw   = cvt + 3932160;
    const bf16* c_xpw    = cvt + 4325376;
    const bf16* c_dtw    = cvt + 4399104;
    const bf16* c_alog   = cvt + 4423680;
    const bf16* c_agg1   = cvt + 4448256;
    const bf16* c_prjw   = cvt + 4644864;
    const bf16* c_convw  = cvt + 4841472;
    const bf16* c_convb  = cvt + 4849152;
    const bf16* c_dtb    = cvt + 4850688;
    const bf16* c_dp     = cvt + 4852224;
    const bf16* c_agb1   = cvt + 4853760;
    const bf16* c_agw2   = cvt + 4854016;
    const bf16* c_agb2   = cvt + 4854784;
    const bf16* c_prjb   = cvt + 4854800;
    const bf16* c_temp   = cvt + 4855056;

    CvtArgs ca;
    for (int i = 0; i < 21; i++) ca.s[i] = d_in[i];
    // merged LN + convert: 12288 LN blocks + 6678 weight-convert blocks
    k_ln_cvt<<<12288 + (1709316 + 255) / 256, 256, 0, stream>>>(ca, flagp, cvt, pooledb, xn);
    k_inproj_t<<<96 * 8, 256, 0, stream>>>(xn, c_inw, xcb, zb);
    k_conv<<<6 * NN * NDI / 8 / 256, 256, 0, stream>>>(xcb, c_convw, c_convb, xab);
    k_xproj_t<<<192 * 4, 256, 0, stream>>>(xab, c_xpw, xpartb);
    k_dt2<<<3072, 256, 0, stream>>>(xpartb, c_dtw, c_dtb, xdblb, dtb);
    k_scan1<<<6 * NCH * 2, 256, 0, stream>>>(dtb, xab, c_alog, xdblb, Hendb, Pprodb);
    k_scomb<<<192, 256, 0, stream>>>(Hendb, Pprodb);
    k_scan2<<<6 * NCH * 2, 256, 0, stream>>>(dtb, xab, zb, xdblb, c_alog, c_dp, Hendb, xcb);
    k_outproj_t<<<96 * 4, 256, 0, stream>>>(xcb, c_outw, c_edge, c_blob, c_spec, procb, pooledb);
    k_final_t<<<32 * 4, 256, 0, stream>>>(procb, c_prjw, c_prjb, pooledb,
                                          c_agg1, c_agb1, c_agw2, c_agb2, c_temp,
                                          flagp, d_out);
}

// Round 16
// 305.975 us; speedup vs baseline: 1.2329x; 1.0226x over previous
//
#include <hip/hip_runtime.h>
#include <hip/hip_bf16.h>

#define NB 2
#define NN 2048
#define ND 256
#define NS 16
#define NDC 4
#define NDI 512
#define NDTR 16
#define LCH 32    // chunk length for parallel scan
#define NCH 64    // number of chunks (LCH*NCH == NN)

typedef __hip_bfloat16 bf16;
typedef __attribute__((ext_vector_type(8))) __bf16 bf16x8;
typedef __attribute__((ext_vector_type(4))) float f32x4;

__device__ __forceinline__ float b2f(bf16 h) { return __bfloat162float(h); }

__device__ __forceinline__ void dec8(const uint4 u, float w[8]) {
    union { unsigned u; float f; } c;
    c.u = u.x << 16;          w[0] = c.f;
    c.u = u.x & 0xffff0000u;  w[1] = c.f;
    c.u = u.y << 16;          w[2] = c.f;
    c.u = u.y & 0xffff0000u;  w[3] = c.f;
    c.u = u.z << 16;          w[4] = c.f;
    c.u = u.z & 0xffff0000u;  w[5] = c.f;
    c.u = u.w << 16;          w[6] = c.f;
    c.u = u.w & 0xffff0000u;  w[7] = c.f;
}

// ---------------- K0+K1 merged: LN+feature-convert (blocks < 12288) | weight convert (rest) ----------------
struct CvtArgs { const void* s[21]; };
__device__ __constant__ const int seg_cum[22] = {
    0, 1048576, 2097152, 3145728, 3146496, 3147264, 3933696, 3939840,
    3941376, 4015104, 4039680, 4041216, 4065792, 4067328, 4460544, 4460545,
    4657153, 4657409, 4658177, 4658180, 4854788, 4855044 };
__device__ __constant__ const int seg_dst[21] = {
    0,        1048576,  2097152,  4847616, 4848384, 3145728, 4841472, 4849152, 4325376,
    4399104,  4850688,  4423680,  4852224, 3932160, 4855056, 4448256, 4853760, 4854016,
    4854784,  4644864,  4854800 };

__global__ __launch_bounds__(256) void k_ln_cvt(
    CvtArgs a, int* __restrict__ flag,
    bf16* __restrict__ cvt, float* __restrict__ pooled, bf16* __restrict__ xn)
{
    int t = threadIdx.x;
    unsigned v0 = ((const unsigned*)a.s[3])[0];
    int f = ((v0 & 0xFFFFu) == 0u);
    if (blockIdx.x >= 12288) {
        // ---- weight conversion path ----
        int idx0 = (blockIdx.x - 12288) * 256 + t;
        if (idx0 == 0) flag[0] = f;
        if (idx0 < 1536) pooled[idx0] = 0.0f;
        int idx = idx0 + 3145728;
        if (idx >= 4855044) return;
        int seg = 3;
        #pragma unroll
        for (int i = 4; i < 21; i++) if (idx >= seg_cum[i]) seg = i;
        int off = idx - seg_cum[seg];
        bf16 v;
        if (f) v = __float2bfloat16(((const float*)a.s[seg])[off]);
        else   v = ((const bf16*)a.s[seg])[off];
        cvt[seg_dst[seg] + off] = v;
        return;
    }
    // ---- layernorm + feature conversion path ----
    int row = blockIdx.x;            // sb*NN + n, sb = s*NB + b
    int sb = row >> 11, n = row & (NN - 1);
    int s = sb >> 1, b = sb & 1;
    const void* xin = a.s[s];
    size_t gi = ((size_t)(b << 11) + n) * ND + t;
    float v = f ? ((const float*)xin)[gi] : b2f(((const bf16*)xin)[gi]);
    cvt[(size_t)s * 1048576 + gi] = __float2bfloat16(v);
    float s1 = v, s2 = v * v;
    #pragma unroll
    for (int m = 1; m < 64; m <<= 1) { s1 += __shfl_xor(s1, m); s2 += __shfl_xor(s2, m); }
    __shared__ float r1[4], r2[4];
    int w = t >> 6;
    if ((t & 63) == 0) { r1[w] = s1; r2[w] = s2; }
    __syncthreads();
    float mean = (r1[0] + r1[1] + r1[2] + r1[3]) * (1.0f / ND);
    float ms   = (r2[0] + r2[1] + r2[2] + r2[3]) * (1.0f / ND);
    float inv = rsqrtf(ms - mean * mean + 1e-5f);
    const void* nw_raw = a.s[3];
    const void* nb_raw = a.s[4];
    float wv = f ? ((const float*)nw_raw)[s * ND + t] : b2f(((const bf16*)nw_raw)[s * ND + t]);
    float bv = f ? ((const float*)nb_raw)[s * ND + t] : b2f(((const bf16*)nb_raw)[s * ND + t]);
    xn[(size_t)row * ND + t] = __float2bfloat16((v - mean) * inv * wv + bv);
}

// ---------------- K2: in_proj tiled MFMA GEMM 128x128 -> xc, z ----------------
__global__ __launch_bounds__(256) void k_inproj_t(
    const bf16* __restrict__ xn, const bf16* __restrict__ in_w,
    bf16* __restrict__ xc, bf16* __restrict__ z)
{
    __shared__ bf16 As[128 * 72];
    __shared__ bf16 Bs[128 * 72];
    int bid = blockIdx.x;
    int bm = bid >> 3, bn = bid & 7;           // 96 x 8
    int m0 = bm * 128, e0 = bn * 128;
    int s = m0 >> 12;
    const bf16* W = in_w + (size_t)s * (2 * NDI) * ND;
    int t = threadIdx.x;
    int w = t >> 6, l = t & 63;
    int wm = w >> 1, wn = w & 1;
    int quad = l >> 4, lan = l & 15;
    f32x4 acc[4][4];
    #pragma unroll
    for (int mi = 0; mi < 4; mi++)
        #pragma unroll
        for (int j = 0; j < 4; j++) acc[mi][j] = (f32x4){0.f, 0.f, 0.f, 0.f};
    for (int kc0 = 0; kc0 < 256; kc0 += 64) {
        __syncthreads();
        #pragma unroll
        for (int i = 0; i < 4; i++) {
            int li = i * 256 + t;
            int row = li >> 3, col = (li & 7) * 8;
            *(uint4*)&As[row * 72 + col] =
                *(const uint4*)(xn + (size_t)(m0 + row) * ND + kc0 + col);
        }
        #pragma unroll
        for (int i = 0; i < 4; i++) {
            int li = i * 256 + t;
            int row = li >> 3, col = (li & 7) * 8;
            *(uint4*)&Bs[row * 72 + col] =
                *(const uint4*)(W + (size_t)(e0 + row) * ND + kc0 + col);
        }
        __syncthreads();
        #pragma unroll
        for (int kc = 0; kc < 64; kc += 32) {
            bf16x8 af[4], bf[4];
            #pragma unroll
            for (int mi = 0; mi < 4; mi++)
                af[mi] = *(const bf16x8*)&As[(wm * 64 + mi * 16 + lan) * 72 + kc + quad * 8];
            #pragma unroll
            for (int j = 0; j < 4; j++)
                bf[j] = *(const bf16x8*)&Bs[(wn * 64 + j * 16 + lan) * 72 + kc + quad * 8];
            #pragma unroll
            for (int mi = 0; mi < 4; mi++)
                #pragma unroll
                for (int j = 0; j < 4; j++)
                    acc[mi][j] = __builtin_amdgcn_mfma_f32_16x16x32_bf16(af[mi], bf[j], acc[mi][j], 0, 0, 0);
        }
    }
    #pragma unroll
    for (int mi = 0; mi < 4; mi++) {
        #pragma unroll
        for (int j = 0; j < 4; j++) {
            int e = e0 + wn * 64 + j * 16 + lan;
            bf16* dst = (e < NDI) ? xc : z;
            int ec = e & (NDI - 1);
            #pragma unroll
            for (int r = 0; r < 4; r++) {
                int m = m0 + wm * 64 + mi * 16 + quad * 4 + r;
                dst[(size_t)m * NDI + ec] = __float2bfloat16(acc[mi][j][r]);
            }
        }
    }
}

// ---------------- K3: causal depthwise conv (DC=4) + silu -> xa, vectorized x8 ----------------
__global__ __launch_bounds__(256) void k_conv(
    const bf16* __restrict__ xc, const bf16* __restrict__ conv_w,
    const bf16* __restrict__ conv_b, bf16* __restrict__ xa)
{
    int idx = blockIdx.x * 256 + threadIdx.x;   // over 6*2048*512/8 = 786432
    int d8 = (idx & 63) * 8;
    int rn = idx >> 6;                          // sb*NN + n
    int n = rn & (NN - 1);
    int sb = rn >> 11;
    int s = sb >> 1;
    const uint4* cwp = (const uint4*)(conv_w + ((size_t)s * NDI + d8) * NDC);
    float cwf[32];
    dec8(cwp[0], cwf); dec8(cwp[1], cwf + 8); dec8(cwp[2], cwf + 16); dec8(cwp[3], cwf + 24);
    float bias[8];
    dec8(*(const uint4*)(conv_b + (size_t)s * NDI + d8), bias);
    size_t g = (size_t)rn * NDI + d8;
    float xv[4][8];   // xv[tau] = x[n-tau]
    #pragma unroll
    for (int tau = 0; tau < 4; tau++) {
        if (n >= tau) dec8(*(const uint4*)(xc + g - (size_t)tau * NDI), xv[tau]);
        else
            #pragma unroll
            for (int j = 0; j < 8; j++) xv[tau][j] = 0.0f;
    }
    union { bf16 h[8]; uint4 u; } o;
    #pragma unroll
    for (int j = 0; j < 8; j++) {
        float a = bias[j];
        #pragma unroll
        for (int k = 0; k < 4; k++) a += cwf[j * 4 + k] * xv[3 - k][j];
        a = a / (1.0f + __expf(-a));
        o.h[j] = __float2bfloat16(a);
    }
    *(uint4*)(xa + g) = o.u;
}

// ---------------- K4a: x_proj MFMA, split-K x4 -> xpart[4][12288][48] fp32 ----------------
__global__ __launch_bounds__(256) void k_xproj_t(
    const bf16* __restrict__ xa, const bf16* __restrict__ xproj_w,
    float* __restrict__ xpart)
{
    __shared__ bf16 As[64 * 72];
    __shared__ bf16 Bs[48 * 72];
    int bid = blockIdx.x;
    int bm = bid >> 2, ks = bid & 3;       // 192 x 4
    int m0 = bm * 64;
    int s = m0 >> 12;
    const bf16* W = xproj_w + (size_t)s * 48 * NDI;
    int t = threadIdx.x;
    int w = t >> 6, l = t & 63;
    int quad = l >> 4, lan = l & 15;
    f32x4 acc[3];
    #pragma unroll
    for (int j = 0; j < 3; j++) acc[j] = (f32x4){0.f, 0.f, 0.f, 0.f};
    for (int kc0 = ks * 128; kc0 < ks * 128 + 128; kc0 += 64) {
        __syncthreads();
        #pragma unroll
        for (int i = 0; i < 2; i++) {          // A: 64x64 = 512 uint4
            int li = i * 256 + t;
            int row = li >> 3, col = (li & 7) * 8;
            *(uint4*)&As[row * 72 + col] =
                *(const uint4*)(xa + (size_t)(m0 + row) * NDI + kc0 + col);
        }
        {
            int li = t;                        // B: 48x64 = 384 uint4
            if (li < 384) {
                int row = li >> 3, col = (li & 7) * 8;
                *(uint4*)&Bs[row * 72 + col] =
                    *(const uint4*)(W + (size_t)row * NDI + kc0 + col);
            }
            int li2 = 256 + t;
            if (li2 < 384) {
                int row = li2 >> 3, col = (li2 & 7) * 8;
                *(uint4*)&Bs[row * 72 + col] =
                    *(const uint4*)(W + (size_t)row * NDI + kc0 + col);
            }
        }
        __syncthreads();
        #pragma unroll
        for (int kc = 0; kc < 64; kc += 32) {
            bf16x8 af = *(const bf16x8*)&As[(w * 16 + lan) * 72 + kc + quad * 8];
            #pragma unroll
            for (int j = 0; j < 3; j++) {
                bf16x8 bf = *(const bf16x8*)&Bs[(j * 16 + lan) * 72 + kc + quad * 8];
                acc[j] = __builtin_amdgcn_mfma_f32_16x16x32_bf16(af, bf, acc[j], 0, 0, 0);
            }
        }
    }
    float* dst = xpart + (size_t)ks * (12288 * 48);
    #pragma unroll
    for (int j = 0; j < 3; j++) {
        int e = j * 16 + lan;
        #pragma unroll
        for (int r = 0; r < 4; r++) {
            int m = m0 + w * 16 + quad * 4 + r;
            dst[(size_t)m * 48 + e] = acc[j][r];
        }
    }
}

// ---------------- K4b: reduce split-K + dt GEMM (K=16) + softplus ----------------
__global__ __launch_bounds__(256) void k_dt2(
    const float* __restrict__ xpart, const bf16* __restrict__ dt_w,
    const bf16* __restrict__ dt_b, float* __restrict__ xdbl, bf16* __restrict__ dt)
{
    __shared__ float xs[4][48];
    int row0 = blockIdx.x * 4;
    int s = row0 >> 12;
    int t = threadIdx.x;
    if (t < 192) {
        int r = t / 48, e = t % 48;
        size_t base = (size_t)(row0 + r) * 48 + e;
        const size_t seg = (size_t)12288 * 48;
        float v = xpart[base] + xpart[base + seg] + xpart[base + 2 * seg] + xpart[base + 3 * seg];
        xs[r][e] = v;
        if (e >= 16) xdbl[base] = v;    // B and C columns for the scans
    }
    __syncthreads();
    #pragma unroll
    for (int dd = 0; dd < 2; dd++) {
        int d = t + dd * 256;
        const uint4* wp = (const uint4*)(dt_w + ((size_t)s * NDI + d) * NDTR);
        float w[16]; dec8(wp[0], w); dec8(wp[1], w + 8);
        float bias = b2f(dt_b[s * NDI + d]);
        #pragma unroll
        for (int r = 0; r < 4; r++) {
            float a = bias;
            #pragma unroll
            for (int j = 0; j < 16; j++) a += w[j] * xs[r][j];
            a = (a > 20.0f) ? a : log1pf(__expf(a));   // softplus
            dt[(size_t)(row0 + r) * NDI + d] = __float2bfloat16(a);
        }
    }
}

// ---------------- K5a: chunk-local scan (LDS-staged) -> Hend, Pprod ----------------
__global__ __launch_bounds__(256) void k_scan1(
    const bf16* __restrict__ dt, const bf16* __restrict__ xa,
    const bf16* __restrict__ A_log, const float* __restrict__ xdbl,
    float* __restrict__ Hend, float* __restrict__ Pprod)
{
    __shared__ bf16 dts[LCH * 256];
    __shared__ bf16 xas[LCH * 256];
    __shared__ float Bs[LCH * NS];
    int bid = blockIdx.x;                 // 6 * NCH * 2 = 768
    int sb = bid / (NCH * 2);
    int rem = bid % (NCH * 2);
    int chunk = rem >> 1, dg = rem & 1;
    int s = sb >> 1;
    int t = threadIdx.x;
    int d = dg * 256 + t;
    int n0 = chunk * LCH;
    size_t rowbase = (size_t)sb * NN;
    const bf16* dtg = dt + (rowbase + n0) * NDI + dg * 256;
    const bf16* xag = xa + (rowbase + n0) * NDI + dg * 256;
    #pragma unroll
    for (int i = 0; i < 4; i++) {
        int li = i * 256 + t;
        int row = li >> 5, q = li & 31;
        ((uint4*)dts)[li] = *(const uint4*)(dtg + (size_t)row * NDI + q * 8);
        ((uint4*)xas)[li] = *(const uint4*)(xag + (size_t)row * NDI + q * 8);
    }
    if (t < 128) {
        int row = t >> 2, q = t & 3;
        ((float4*)Bs)[t] = ((const float4*)(xdbl + (rowbase + n0 + row) * 48 + 16))[q];
    }
    float A[16];
    {
        const uint4* ap = (const uint4*)(A_log + ((size_t)s * NDI + d) * NS);
        float al[8]; dec8(ap[0], al);
        #pragma unroll
        for (int i = 0; i < 8; i++) A[i] = -__expf(al[i]);
        dec8(ap[1], al);
        #pragma unroll
        for (int i = 0; i < 8; i++) A[8 + i] = -__expf(al[i]);
    }
    __syncthreads();
    float h[16], P[16];
    #pragma unroll
    for (int i = 0; i < 16; i++) { h[i] = 0.0f; P[i] = 1.0f; }
    #pragma unroll 4
    for (int nl = 0; nl < LCH; nl++) {
        float dtv = b2f(dts[nl * 256 + t]);
        float xav = b2f(xas[nl * 256 + t]);
        float bcom = dtv * xav;
        const float4* br = (const float4*)&Bs[nl * NS];
        float4 b0 = br[0], b1 = br[1], b2 = br[2], b3 = br[3];
        float bv[16] = {b0.x,b0.y,b0.z,b0.w,b1.x,b1.y,b1.z,b1.w,
                        b2.x,b2.y,b2.z,b2.w,b3.x,b3.y,b3.z,b3.w};
        #pragma unroll
        for (int st = 0; st < 16; st++) {
            float dA = __expf(dtv * A[st]);
            h[st] = dA * h[st] + bcom * bv[st];
            P[st] *= dA;
        }
    }
    size_t base = ((size_t)(chunk * 6 + sb) * NS) * NDI + d;
    #pragma unroll
    for (int st = 0; st < 16; st++) {
        Hend[base + (size_t)st * NDI] = h[st];
        Pprod[base + (size_t)st * NDI] = P[st];
    }
}

// ---------------- K5b: prefix over chunk summaries, parallel over states ----------------
__global__ __launch_bounds__(256) void k_scomb(float* __restrict__ Hend, const float* __restrict__ Pprod)
{
    int idx = blockIdx.x * 256 + threadIdx.x;   // 49152 = 6 sb * 16 st * 512 d
    int sb = idx >> 13;
    int rem = idx & 8191;
    int st = rem >> 9, d = rem & 511;
    float h = 0.0f;
    const size_t stride = (size_t)6 * NS * NDI;
    size_t g = ((size_t)sb * NS + st) * NDI + d;
    #pragma unroll 4
    for (int c = 0; c < NCH; c++) {
        float He = Hend[g], Pp = Pprod[g];
        Hend[g] = h;                 // h_start for this chunk
        h = He + Pp * h;
        g += stride;
    }
}

// ---------------- K5c: re-scan chunks from h_start (LDS-staged), C-dot + gating -> y ----------------
__global__ __launch_bounds__(256) void k_scan2(
    const bf16* __restrict__ dt, const bf16* __restrict__ xa, const bf16* __restrict__ z,
    const float* __restrict__ xdbl,
    const bf16* __restrict__ A_log, const bf16* __restrict__ Dp,
    const float* __restrict__ Hstart, bf16* __restrict__ y)
{
    __shared__ bf16 dts[LCH * 256];
    __shared__ bf16 xas[LCH * 256];
    __shared__ bf16 zs[LCH * 256];
    __shared__ float Bs[LCH * NS], Cs[LCH * NS];
    int bid = blockIdx.x;
    int sb = bid / (NCH * 2);
    int rem = bid % (NCH * 2);
    int chunk = rem >> 1, dg = rem & 1;
    int s = sb >> 1;
    int t = threadIdx.x;
    int d = dg * 256 + t;
    int n0 = chunk * LCH;
    size_t rowbase = (size_t)sb * NN;
    const bf16* dtg = dt + (rowbase + n0) * NDI + dg * 256;
    const bf16* xag = xa + (rowbase + n0) * NDI + dg * 256;
    const bf16* zg  = z  + (rowbase + n0) * NDI + dg * 256;
    #pragma unroll
    for (int i = 0; i < 4; i++) {
        int li = i * 256 + t;
        int row = li >> 5, q = li & 31;
        ((uint4*)dts)[li] = *(const uint4*)(dtg + (size_t)row * NDI + q * 8);
        ((uint4*)xas)[li] = *(const uint4*)(xag + (size_t)row * NDI + q * 8);
        ((uint4*)zs)[li]  = *(const uint4*)(zg  + (size_t)row * NDI + q * 8);
    }
    if (t < 128) {
        int row = t >> 2, q = t & 3;
        ((float4*)Bs)[t] = ((const float4*)(xdbl + (rowbase + n0 + row) * 48 + 16))[q];
    } else {
        int t2 = t - 128;
        int row = t2 >> 2, q = t2 & 3;
        ((float4*)Cs)[t2] = ((const float4*)(xdbl + (rowbase + n0 + row) * 48 + 32))[q];
    }
    float A[16];
    {
        const uint4* ap = (const uint4*)(A_log + ((size_t)s * NDI + d) * NS);
        float al[8]; dec8(ap[0], al);
        #pragma unroll
        for (int i = 0; i < 8; i++) A[i] = -__expf(al[i]);
        dec8(ap[1], al);
        #pragma unroll
        for (int i = 0; i < 8; i++) A[8 + i] = -__expf(al[i]);
    }
    float Dpv = b2f(Dp[s * NDI + d]);
    float h[16];
    {
        size_t base = ((size_t)(chunk * 6 + sb) * NS) * NDI + d;
        #pragma unroll
        for (int st = 0; st < 16; st++) h[st] = Hstart[base + (size_t)st * NDI];
    }
    __syncthreads();
    bf16* yp = y + (rowbase + n0) * NDI + d;
    #pragma unroll 4
    for (int nl = 0; nl < LCH; nl++) {
        float dtv = b2f(dts[nl * 256 + t]);
        float xav = b2f(xas[nl * 256 + t]);
        float zz  = b2f(zs[nl * 256 + t]);
        float bcom = dtv * xav;
        const float4* br = (const float4*)&Bs[nl * NS];
        const float4* cr = (const float4*)&Cs[nl * NS];
        float4 b0 = br[0], b1 = br[1], b2 = br[2], b3 = br[3];
        float4 c0 = cr[0], c1 = cr[1], c2 = cr[2], c3 = cr[3];
        float bv[16] = {b0.x,b0.y,b0.z,b0.w,b1.x,b1.y,b1.z,b1.w,
                        b2.x,b2.y,b2.z,b2.w,b3.x,b3.y,b3.z,b3.w};
        float cv[16] = {c0.x,c0.y,c0.z,c0.w,c1.x,c1.y,c1.z,c1.w,
                        c2.x,c2.y,c2.z,c2.w,c3.x,c3.y,c3.z,c3.w};
        float yacc = 0.0f;
        #pragma unroll
        for (int st = 0; st < 16; st++) {
            float dA = __expf(dtv * A[st]);
            h[st] = dA * h[st] + bcom * bv[st];
            yacc += h[st] * cv[st];
        }
        float yv = yacc + xav * Dpv;
        yv *= zz / (1.0f + __expf(-zz));
        yp[(size_t)nl * NDI] = __float2bfloat16(yv);
    }
}

// ---------------- K6: out_proj tiled MFMA + residual -> proc, fused pooling ----------------
__global__ __launch_bounds__(256) void k_outproj_t(
    const bf16* __restrict__ y, const bf16* __restrict__ out_w,
    const bf16* __restrict__ e_, const bf16* __restrict__ bl, const bf16* __restrict__ sp,
    bf16* __restrict__ proc, float* __restrict__ pooled)
{
    __shared__ bf16 As[128 * 72];
    __shared__ bf16 Bs[64 * 72];
    __shared__ float colsum[64];
    int bid = blockIdx.x;
    int bm = bid >> 2, bn = bid & 3;
    int m0 = bm * 128, e0 = bn * 64;
    int s = m0 >> 12;
    const bf16* W = out_w + (size_t)s * ND * NDI;
    int t = threadIdx.x;
    int w = t >> 6, l = t & 63;
    int quad = l >> 4, lan = l & 15;
    f32x4 acc[2][4];
    #pragma unroll
    for (int mi = 0; mi < 2; mi++)
        #pragma unroll
        for (int j = 0; j < 4; j++) acc[mi][j] = (f32x4){0.f, 0.f, 0.f, 0.f};
    for (int kc0 = 0; kc0 < 512; kc0 += 64) {
        __syncthreads();
        #pragma unroll
        for (int i = 0; i < 4; i++) {
            int li = i * 256 + t;
            int row = li >> 3, col = (li & 7) * 8;
            *(uint4*)&As[row * 72 + col] =
                *(const uint4*)(y + (size_t)(m0 + row) * NDI + kc0 + col);
        }
        #pragma unroll
        for (int i = 0; i < 2; i++) {
            int li = i * 256 + t;
            int row = li >> 3, col = (li & 7) * 8;
            *(uint4*)&Bs[row * 72 + col] =
                *(const uint4*)(W + (size_t)(e0 + row) * NDI + kc0 + col);
        }
        __syncthreads();
        #pragma unroll
        for (int kc = 0; kc < 64; kc += 32) {
            bf16x8 af[2], bf[4];
            #pragma unroll
            for (int mi = 0; mi < 2; mi++)
                af[mi] = *(const bf16x8*)&As[(w * 32 + mi * 16 + lan) * 72 + kc + quad * 8];
            #pragma unroll
            for (int j = 0; j < 4; j++)
                bf[j] = *(const bf16x8*)&Bs[(j * 16 + lan) * 72 + kc + quad * 8];
            #pragma unroll
            for (int mi = 0; mi < 2; mi++)
                #pragma unroll
                for (int j = 0; j < 4; j++)
                    acc[mi][j] = __builtin_amdgcn_mfma_f32_16x16x32_bf16(af[mi], bf[j], acc[mi][j], 0, 0, 0);
        }
    }
    if (t < 64) colsum[t] = 0.0f;
    __syncthreads();
    const bf16* xin = (s == 0) ? e_ : ((s == 1) ? bl : sp);
    int b = (m0 >> 11) & 1;
    #pragma unroll
    for (int mi = 0; mi < 2; mi++) {
        #pragma unroll
        for (int j = 0; j < 4; j++) {
            int e = e0 + j * 16 + lan;
            float ps = 0.0f;
            #pragma unroll
            for (int r = 0; r < 4; r++) {
                int m = m0 + w * 32 + mi * 16 + quad * 4 + r;
                int n = m & (NN - 1);
                float v = acc[mi][j][r] + b2f(xin[((size_t)(b * NN + n)) * ND + e]);
                proc[(size_t)m * ND + e] = __float2bfloat16(v);
                ps += v;
            }
            atomicAdd(&colsum[j * 16 + lan], ps);
        }
    }
    __syncthreads();
    if (t < 64) atomicAdd(&pooled[b * 768 + s * 256 + e0 + t], colsum[t]);
}

// ---------------- K9: final proj MFMA 64x64 tiles (256 blocks); coeff dot interleaved ----------------
__global__ __launch_bounds__(256) void k_final_t(
    const bf16* __restrict__ proc, const bf16* __restrict__ proj_w,
    const bf16* __restrict__ proj_b, const float* __restrict__ pooled,
    const bf16* __restrict__ agg_w1, const bf16* __restrict__ agg_b1,
    const bf16* __restrict__ agg_w2, const bf16* __restrict__ agg_b2,
    const bf16* __restrict__ temp,
    const int* __restrict__ flag, void* __restrict__ out)
{
    __shared__ bf16 As[64 * 72];
    __shared__ bf16 Bs[64 * 72];
    __shared__ float hb[256];
    __shared__ float lg[3];
    __shared__ float cf[3];
    int bid = blockIdx.x;
    int bm = bid >> 2, bn = bid & 3;       // 64 x 4
    int m0 = bm * 64, e0 = bn * 64;
    int b = m0 >> 11;                 // batch, const per block
    int nbase = m0 & (NN - 1);
    int t = threadIdx.x;
    int w = t >> 6, l = t & 63;
    int quad = l >> 4, lan = l & 15;
    // coeff dot state (interleaved into K-loop below; VALU work hides under MFMA per m114)
    float dot = 0.0f;
    const uint4* awp = (const uint4*)(agg_w1 + (size_t)t * 768);
    const float* pp0 = pooled + b * 768;
    f32x4 acc[4];
    #pragma unroll
    for (int j = 0; j < 4; j++) acc[j] = (f32x4){0.f, 0.f, 0.f, 0.f};
    for (int kc0 = 0; kc0 < 768; kc0 += 64) {
        int sA = kc0 >> 8, kd0 = kc0 & 255;
        const bf16* Asrc = proc + ((size_t)(sA * NB + b) * NN + nbase) * ND + kd0;
        __syncthreads();
        #pragma unroll
        for (int i = 0; i < 2; i++) {          // A: 64x64 = 512 uint4
            int li = i * 256 + t;
            int row = li >> 3, col = (li & 7) * 8;
            *(uint4*)&As[row * 72 + col] = *(const uint4*)(Asrc + (size_t)row * ND + col);
        }
        #pragma unroll
        for (int i = 0; i < 2; i++) {          // B: 64x64
            int li = i * 256 + t;
            int row = li >> 3, col = (li & 7) * 8;
            *(uint4*)&Bs[row * 72 + col] =
                *(const uint4*)(proj_w + (size_t)(e0 + row) * 768 + kc0 + col);
        }
        __syncthreads();
        #pragma unroll
        for (int kc = 0; kc < 64; kc += 32) {
            bf16x8 af = *(const bf16x8*)&As[(w * 16 + lan) * 72 + kc + quad * 8];
            bf16x8 bf[4];
            #pragma unroll
            for (int j = 0; j < 4; j++)
                bf[j] = *(const bf16x8*)&Bs[(j * 16 + lan) * 72 + kc + quad * 8];
            #pragma unroll
            for (int j = 0; j < 4; j++)
                acc[j] = __builtin_amdgcn_mfma_f32_16x16x32_bf16(af, bf[j], acc[j], 0, 0, 0);
        }
        // interleaved coeff-dot chunk: 8 x uint4 of agg_w1 row per K-iteration
        {
            int k8base = (kc0 >> 6) * 8;
            #pragma unroll
            for (int k8 = k8base; k8 < k8base + 8; k8++) {
                float wv[8]; dec8(awp[k8], wv);
                const float* pp = pp0 + k8 * 8;
                #pragma unroll
                for (int j = 0; j < 8; j++) dot += wv[j] * pp[j];
            }
        }
    }
    // ---- finish coeffs (cheap): gelu -> 3-dot -> double softmax ----
    {
        float x = b2f(agg_b1[t]) + dot * (1.0f / NN);
        float inner = 0.7978845608028654f * (x + 0.044715f * x * x * x);
        hb[t] = 0.5f * x * (1.0f + tanhf(inner));
        __syncthreads();
        if (t < 3) {
            float ll = b2f(agg_b2[t]);
            const bf16* w2 = agg_w2 + t * 256;
            for (int d2 = 0; d2 < 256; d2++) ll += b2f(w2[d2]) * hb[d2];
            lg[t] = ll;
        }
        __syncthreads();
        if (t == 0) {
            float m = fmaxf(lg[0], fmaxf(lg[1], lg[2]));
            float e0f = __expf(lg[0] - m), e1 = __expf(lg[1] - m), e2 = __expf(lg[2] - m);
            float iS = 1.0f / (e0f + e1 + e2);
            float c0 = e0f * iS, c1 = e1 * iS, c2 = e2 * iS;
            float tt = b2f(temp[0]) + 1e-6f;
            float m2 = fmaxf(c0, fmaxf(c1, c2)) / tt;
            e0f = __expf(c0 / tt - m2); e1 = __expf(c1 / tt - m2); e2 = __expf(c2 / tt - m2);
            iS = 1.0f / (e0f + e1 + e2);
            cf[0] = e0f * iS; cf[1] = e1 * iS; cf[2] = e2 * iS;
        }
        __syncthreads();
    }
    float c0 = cf[0], c1 = cf[1], c2 = cf[2];
    int f = flag[0];
    #pragma unroll
    for (int j = 0; j < 4; j++) {
        int e = e0 + j * 16 + lan;
        float pb = b2f(proj_b[e]);
        #pragma unroll
        for (int r = 0; r < 4; r++) {
            int m = m0 + w * 16 + quad * 4 + r;
            int n = m & (NN - 1);
            size_t pbase = ((size_t)b * NN + n) * ND + e;
            float wres = c0 * b2f(proc[pbase])
                       + c1 * b2f(proc[pbase + (size_t)1 * NB * NN * ND])
                       + c2 * b2f(proc[pbase + (size_t)2 * NB * NN * ND]);
            float v = acc[j][r] + pb + wres;
            if (f) ((float*)out)[(size_t)m * ND + e] = v;
            else   ((bf16*)out)[(size_t)m * ND + e] = __float2bfloat16(v);
        }
    }
}

extern "C" void kernel_launch(void* const* d_in, const int* in_sizes, int n_in,
                              void* d_out, int out_size, void* d_ws, size_t ws_size,
                              hipStream_t stream)
{
    // ---- workspace layout (bytes), total ~103.3 MB (ws is ~256 MB) ----
    char* w8 = (char*)d_ws;
    int*   flagp   = (int*)(w8);
    bf16*  cvt     = (bf16*)(w8 + 16);              // 9,710,144 B
    bf16*  xn      = (bf16*)(w8 + 9710160);         // 6,291,456 B (xn -> proc)
    bf16*  xcb     = (bf16*)(w8 + 16001616);        // 12,582,912 B (xc, then y)
    bf16*  zb      = (bf16*)(w8 + 28584528);
    bf16*  xab     = (bf16*)(w8 + 41167440);
    bf16*  dtb     = (bf16*)(w8 + 53750352);
    float* xdblb   = (float*)(w8 + 66333264);       // 2,359,296 B
    float* pooledb = (float*)(w8 + 68692560);       // 6,144 B
    float* Hendb   = (float*)(w8 + 68698736);       // 12,582,912 B
    float* Pprodb  = (float*)(w8 + 81281648);       // 12,582,912 B
    float* xpartb  = (float*)(w8 + 93864560);       // 9,437,184 B -> end 103,301,744
    bf16*  procb   = xn;                            // proc after scan2 completes

    const bf16* c_edge   = cvt + 0;
    const bf16* c_blob   = cvt + 1048576;
    const bf16* c_spec   = cvt + 2097152;
    const bf16* c_inw    = cvt + 3145728;
    const bf16* c_outw   = cvt + 3932160;
    const bf16* c_xpw    = cvt + 4325376;
    const bf16* c_dtw    = cvt + 4399104;
    const bf16* c_alog   = cvt + 4423680;
    const bf16* c_agg1   = cvt + 4448256;
    const bf16* c_prjw   = cvt + 4644864;
    const bf16* c_convw  = cvt + 4841472;
    const bf16* c_convb  = cvt + 4849152;
    const bf16* c_dtb    = cvt + 4850688;
    const bf16* c_dp     = cvt + 4852224;
    const bf16* c_agb1   = cvt + 4853760;
    const bf16* c_agw2   = cvt + 4854016;
    const bf16* c_agb2   = cvt + 4854784;
    const bf16* c_prjb   = cvt + 4854800;
    const bf16* c_temp   = cvt + 4855056;

    CvtArgs ca;
    for (int i = 0; i < 21; i++) ca.s[i] = d_in[i];
    // merged LN + convert: 12288 LN blocks + 6678 weight-convert blocks
    k_ln_cvt<<<12288 + (1709316 + 255) / 256, 256, 0, stream>>>(ca, flagp, cvt, pooledb, xn);
    k_inproj_t<<<96 * 8, 256, 0, stream>>>(xn, c_inw, xcb, zb);
    k_conv<<<6 * NN * NDI / 8 / 256, 256, 0, stream>>>(xcb, c_convw, c_convb, xab);
    k_xproj_t<<<192 * 4, 256, 0, stream>>>(xab, c_xpw, xpartb);
    k_dt2<<<3072, 256, 0, stream>>>(xpartb, c_dtw, c_dtb, xdblb, dtb);
    k_scan1<<<6 * NCH * 2, 256, 0, stream>>>(dtb, xab, c_alog, xdblb, Hendb, Pprodb);
    k_scomb<<<192, 256, 0, stream>>>(Hendb, Pprodb);
    k_scan2<<<6 * NCH * 2, 256, 0, stream>>>(dtb, xab, zb, xdblb, c_alog, c_dp, Hendb, xcb);
    k_outproj_t<<<96 * 4, 256, 0, stream>>>(xcb, c_outw, c_edge, c_blob, c_spec, procb, pooledb);
    k_final_t<<<64 * 4, 256, 0, stream>>>(procb, c_prjw, c_prjb, pooledb,
                                          c_agg1, c_agb1, c_agw2, c_agb2, c_temp,
                                          flagp, d_out);
}